// Round 19
// baseline (492.537 us; speedup 1.0000x reference)
//
#include <hip/hip_runtime.h>
#include <hip/hip_fp16.h>
#include <math.h>

#define ISQ2 0.70710678118654752440f

typedef _Float16 f16x8 __attribute__((ext_vector_type(8)));
typedef __attribute__((ext_vector_type(4))) float f32x4;

static __device__ __constant__ float H0c[13] = {
    -0.0017578f, 0.0f, 0.0222656f, -0.046875f, -0.0482422f, 0.296875f,
    0.5554688f, 0.296875f, -0.0482422f, -0.046875f, 0.0222656f, 0.0f, -0.0017578f};
static __device__ __constant__ float H1c[19] = {
    -7.06e-05f, 0.0f, 0.0013419f, -0.0018834f, -0.0071568f, 0.023856f,
    0.0556431f, -0.0516881f, -0.2997576f, 0.5594308f, -0.2997576f, -0.0516881f,
    0.0556431f, 0.023856f, -0.0071568f, -0.0018834f, 0.0013419f, 0.0f, -7.06e-05f};

__device__ __forceinline__ int refl32(int i) {
    if (i < 0) i = -1 - i;
    if (i > 31) i = 63 - i;
    return i;
}

// tanh-form GELU: |err| < ~1e-3 vs exact erf form
__device__ __forceinline__ float gelu_fast(float x) {
    float u = x * (0.7978845608f + 0.0356774081f * x * x);
    float e = __expf(-2.0f * fabsf(u));
    float t = 1.0f - 2.0f * e / (1.0f + e);
    t = copysignf(t, u);
    return 0.5f * x * (1.0f + t);
}

__device__ __forceinline__ __half2 u2h2(unsigned int u) {
    union { unsigned int u; __half2 h; } c;
    c.u = u;
    return c.h;
}

// ---------------- K1: LN1 + transpose (B,N,C)->(B,C,32,32) fp16 --------------
__global__ __launch_bounds__(256) void k_ln1_t(const float* __restrict__ x,
                                               const float* __restrict__ g,
                                               const float* __restrict__ be,
                                               __half* __restrict__ Ah) {
    __shared__ float sx[64][65];
    __shared__ float rs[64][4], rq[64][4];
    __shared__ float sm[64], sv[64];
    int b = blockIdx.x >> 4;
    int n0 = (blockIdx.x & 15) << 6;
    int tid = threadIdx.x;
    const float* xp = x + ((size_t)b * 1024 + n0) * 64;
#pragma unroll
    for (int rep = 0; rep < 16; ++rep) {
        int idx = rep * 256 + tid;
        sx[idx >> 6][idx & 63] = xp[idx];
    }
    __syncthreads();
    {
        int i = tid >> 2, q = tid & 3;
        float s = 0.f, ss = 0.f;
#pragma unroll
        for (int d = 0; d < 16; ++d) {
            float v = sx[i][q * 16 + d];
            s += v; ss += v * v;
        }
        rs[i][q] = s; rq[i][q] = ss;
    }
    __syncthreads();
    if (tid < 64) {
        float s = rs[tid][0] + rs[tid][1] + rs[tid][2] + rs[tid][3];
        float ss = rq[tid][0] + rq[tid][1] + rq[tid][2] + rq[tid][3];
        float m = s * (1.f / 64.f);
        float v = ss * (1.f / 64.f) - m * m;
        sm[tid] = m;
        sv[tid] = rsqrtf(v + 1e-5f);
    }
    __syncthreads();
#pragma unroll
    for (int rep = 0; rep < 16; ++rep) {
        int idx = rep * 256 + tid;
        int c = idx >> 6, i = idx & 63;
        float val = (sx[i][c] - sm[i]) * sv[i] * g[c] + be[c];
        Ah[((size_t)(b * 64 + c)) * 1024 + n0 + i] = __float2half(val);
    }
}

// ---------------- K2: forward DTCWT (fp16 in/out), sliding windows ------------
__global__ __launch_bounds__(256, 4) void k_fwd(const __half* __restrict__ Ah,
                                                const float* __restrict__ wll,
                                                float* __restrict__ LL,
                                                __half* __restrict__ HSr,
                                                __half* __restrict__ HSi) {
    __shared__ float sx[32][52];
    __shared__ float slo[50][34];
    __shared__ float shi[50][34];
    int bc = blockIdx.x;
    int c = bc & 63;
    int tid = threadIdx.x;
    int hA = tid >> 3, w0r = (tid & 7) * 4;
    {
        const __half2* ap2 = (const __half2*)(Ah + (size_t)bc * 1024);
        __half2 v01 = ap2[tid * 2], v23 = ap2[tid * 2 + 1];
        sx[hA][w0r + 9] = __low2float(v01);
        sx[hA][w0r + 10] = __high2float(v01);
        sx[hA][w0r + 11] = __low2float(v23);
        sx[hA][w0r + 12] = __high2float(v23);
    }
    __syncthreads();
    for (int i = tid; i < 576; i += 256) {
        int h = i / 18, j = i - (i / 18) * 18;
        int wp = (j < 9) ? (j - 9) : (23 + j);
        sx[h][wp + 9] = sx[h][refl32(wp) + 9];
    }
    __syncthreads();
    {
        float ws[22];
#pragma unroll
        for (int t = 0; t < 22; ++t) ws[t] = sx[hA][w0r + t];
        float lo[4] = {0.f, 0.f, 0.f, 0.f}, hi[4] = {0.f, 0.f, 0.f, 0.f};
#pragma unroll
        for (int k = 0; k < 19; ++k)
#pragma unroll
            for (int j = 0; j < 4; ++j) hi[j] += H1c[k] * ws[j + k];
#pragma unroll
        for (int k = 0; k < 13; ++k)
#pragma unroll
            for (int j = 0; j < 4; ++j) lo[j] += H0c[k] * ws[j + k + 3];
#pragma unroll
        for (int j = 0; j < 4; ++j) {
            slo[hA + 9][w0r + j] = lo[j];
            shi[hA + 9][w0r + j] = hi[j];
        }
    }
    __syncthreads();
    for (int i = tid; i < 576; i += 256) {
        int j = i >> 5, w = i & 31;
        int hp = (j < 9) ? (j - 9) : (23 + j);
        int hs = refl32(hp);
        slo[hp + 9][w] = slo[hs + 9][w];
        shi[hp + 9][w] = shi[hs + 9][w];
    }
    __syncthreads();
    {
        int wL = tid & 31, h0 = (tid >> 5) * 4;
        float cs[16];
#pragma unroll
        for (int t = 0; t < 16; ++t) cs[t] = slo[h0 + 3 + t][wL];
#pragma unroll
        for (int j = 0; j < 4; ++j) {
            float acc = 0.f;
#pragma unroll
            for (int k = 0; k < 13; ++k) acc += H0c[k] * cs[j + k];
            int p = (h0 + j) * 32 + wL;
            LL[(size_t)bc * 1024 + p] = acc * wll[c * 1024 + p];
        }
    }
    {
        int i = tid >> 4, j = tid & 15;
        size_t base = (size_t)bc * 1536 + tid;
        float a, bb, cc2, dd;
        {
            float2 sl[20];
#pragma unroll
            for (int t = 0; t < 20; ++t) sl[t] = *(const float2*)&slo[2 * i + t][2 * j];
            a = bb = cc2 = dd = 0.f;
#pragma unroll
            for (int k = 0; k < 19; ++k) {
                a += H1c[k] * sl[k].x;
                bb += H1c[k] * sl[k].y;
                cc2 += H1c[k] * sl[k + 1].x;
                dd += H1c[k] * sl[k + 1].y;
            }
            HSr[base + 0 * 256] = __float2half((a - dd) * ISQ2);
            HSi[base + 0 * 256] = __float2half((bb + cc2) * ISQ2);
            HSr[base + 5 * 256] = __float2half((a + dd) * ISQ2);
            HSi[base + 5 * 256] = __float2half((bb - cc2) * ISQ2);
        }
        {
            float2 sh[20];
#pragma unroll
            for (int t = 0; t < 20; ++t) sh[t] = *(const float2*)&shi[2 * i + t][2 * j];
            a = bb = cc2 = dd = 0.f;
#pragma unroll
            for (int k = 0; k < 19; ++k) {
                a += H1c[k] * sh[k].x;
                bb += H1c[k] * sh[k].y;
                cc2 += H1c[k] * sh[k + 1].x;
                dd += H1c[k] * sh[k + 1].y;
            }
            HSr[base + 1 * 256] = __float2half((a - dd) * ISQ2);
            HSi[base + 1 * 256] = __float2half((bb + cc2) * ISQ2);
            HSr[base + 4 * 256] = __float2half((a + dd) * ISQ2);
            HSi[base + 4 * 256] = __float2half((bb - cc2) * ISQ2);
            a = bb = cc2 = dd = 0.f;
#pragma unroll
            for (int k = 0; k < 13; ++k) {
                a += H0c[k] * sh[k + 3].x;
                bb += H0c[k] * sh[k + 3].y;
                cc2 += H0c[k] * sh[k + 4].x;
                dd += H0c[k] * sh[k + 4].y;
            }
            HSr[base + 2 * 256] = __float2half((a - dd) * ISQ2);
            HSi[base + 2 * 256] = __float2half((bb + cc2) * ISQ2);
            HSr[base + 3 * 256] = __float2half((a + dd) * ISQ2);
            HSi[base + 3 * 256] = __float2half((bb - cc2) * ISQ2);
        }
    }
}

// ---------------- K2b: prep complex-MLP fp16 B-frags (runs AFTER k_fwd) -------
__global__ __launch_bounds__(256) void k_prep_mlp(const float* __restrict__ mw1,
                                                  const float* __restrict__ mw2,
                                                  __half* __restrict__ W1cr,
                                                  __half* __restrict__ W1ci,
                                                  __half* __restrict__ W2cr,
                                                  __half* __restrict__ W2ci) {
    int gid = blockIdx.x * 256 + threadIdx.x;
    int stride = gridDim.x * 256;
    for (int i = gid; i < 2048; i += stride) {
        int q = i >> 9, rest = i & 511;
        int n = rest >> 5, k = rest & 31;
        if (k < 16) {
            W1cr[i] = __float2half(mw1[q * 256 + k * 16 + n]);
            W1ci[i] = __float2half(mw1[1024 + q * 256 + k * 16 + n]);
            W2cr[i] = __float2half(mw2[q * 256 + k * 16 + n]);
            W2ci[i] = __float2half(mw2[1024 + q * 256 + k * 16 + n]);
        } else {
            W1cr[i] = __float2half(-mw1[1024 + q * 256 + (k - 16) * 16 + n]);
            W1ci[i] = __float2half(mw1[q * 256 + (k - 16) * 16 + n]);
            W2cr[i] = __float2half(-mw2[1024 + q * 256 + (k - 16) * 16 + n]);
            W2ci[i] = __float2half(mw2[q * 256 + (k - 16) * 16 + n]);
        }
    }
}

// ---------------- K3: complex block-MLP via MFMA, fp16 HS in/out --------------
__global__ __launch_bounds__(256) void k_mlpm(__half* __restrict__ HSr,
                                              __half* __restrict__ HSi,
                                              const __half* __restrict__ W1cr,
                                              const __half* __restrict__ W1ci,
                                              const __half* __restrict__ W2cr,
                                              const __half* __restrict__ W2ci,
                                              const float* __restrict__ b1,
                                              const float* __restrict__ b2) {
    __shared__ __half xh[4][64][40];
    int tid = threadIdx.x;
    int wid = tid >> 6, lane = tid & 63;
    int lr = lane & 15, kg = lane >> 4;
    int b = blockIdx.x / 6;
    int o = blockIdx.x - b * 6;
    size_t base = (size_t)b * 98304 + (size_t)o * 256;

#pragma unroll 1
    for (int q = 0; q < 4; ++q) {
#pragma unroll
        for (int mt = 0; mt < 4; ++mt) {
            int token0 = wid * 64 + mt * 16;
            const unsigned short* src =
                (const unsigned short*)((kg < 2) ? HSr : HSi);
            int c0 = q * 16 + (kg & 1) * 8;
            unsigned int u[4];
#pragma unroll
            for (int e = 0; e < 4; ++e) {
                unsigned int lo = src[base + (size_t)(c0 + 2 * e) * 1536 + token0 + lr];
                unsigned int hi = src[base + (size_t)(c0 + 2 * e + 1) * 1536 + token0 + lr];
                u[e] = lo | (hi << 16);
            }
            uint4 av = make_uint4(u[0], u[1], u[2], u[3]);
            f16x8 a = *(f16x8*)&av;
            f16x8 bfr = *(const f16x8*)(W1cr + q * 512 + lr * 32 + kg * 8);
            f16x8 bfi = *(const f16x8*)(W1ci + q * 512 + lr * 32 + kg * 8);
            f32x4 accr = (f32x4){0.f, 0.f, 0.f, 0.f};
            f32x4 acci = (f32x4){0.f, 0.f, 0.f, 0.f};
            accr = __builtin_amdgcn_mfma_f32_16x16x32_f16(a, bfr, accr, 0, 0, 0);
            acci = __builtin_amdgcn_mfma_f32_16x16x32_f16(a, bfi, acci, 0, 0, 0);
            float b1r = b1[q * 16 + lr];
            float b1i = b1[64 + q * 16 + lr];
#pragma unroll
            for (int reg = 0; reg < 4; ++reg) {
                int tl = mt * 16 + kg * 4 + reg;
                xh[wid][tl][lr] = __float2half(fmaxf(accr[reg] + b1r, 0.f));
                xh[wid][tl][16 + lr] = __float2half(fmaxf(acci[reg] + b1i, 0.f));
            }
        }
        __syncthreads();
#pragma unroll
        for (int mt = 0; mt < 4; ++mt) {
            f16x8 a = *(const f16x8*)&xh[wid][mt * 16 + lr][kg * 8];
            f16x8 bfr = *(const f16x8*)(W2cr + q * 512 + lr * 32 + kg * 8);
            f16x8 bfi = *(const f16x8*)(W2ci + q * 512 + lr * 32 + kg * 8);
            f32x4 accr = (f32x4){0.f, 0.f, 0.f, 0.f};
            f32x4 acci = (f32x4){0.f, 0.f, 0.f, 0.f};
            accr = __builtin_amdgcn_mfma_f32_16x16x32_f16(a, bfr, accr, 0, 0, 0);
            acci = __builtin_amdgcn_mfma_f32_16x16x32_f16(a, bfi, acci, 0, 0, 0);
            float b2r = b2[q * 16 + lr];
            float b2i = b2[64 + q * 16 + lr];
            size_t cb = base + (size_t)(q * 16 + lr) * 1536 + wid * 64 + mt * 16 + kg * 4;
#pragma unroll
            for (int reg = 0; reg < 4; ++reg) {
                HSr[cb + reg] = __float2half(accr[reg] + b2r);
                HSi[cb + reg] = __float2half(acci[reg] + b2i);
            }
        }
        __syncthreads();
    }
}

// ---------------- K4: inverse DTCWT (fp16 in/out), sliding windows ------------
__global__ __launch_bounds__(256, 4) void k_inv(const float* __restrict__ LL,
                                                const __half* __restrict__ HSr,
                                                const __half* __restrict__ HSi,
                                                __half* __restrict__ Yh) {
    __shared__ float sll[50][34], slh[50][34], shl[50][34], shh[50][34];
    __shared__ float slo[32][52], shi[32][52];
    int bc = blockIdx.x;
    int tid = threadIdx.x;
    int hA = tid >> 3, w0r = (tid & 7) * 4;
    {
        const float4* lp4 = (const float4*)(LL + (size_t)bc * 1024);
        float4 v = lp4[tid];
        sll[hA + 9][w0r] = v.x;
        sll[hA + 9][w0r + 1] = v.y;
        sll[hA + 9][w0r + 2] = v.z;
        sll[hA + 9][w0r + 3] = v.w;
    }
    {
        int i = tid >> 4, j = tid & 15;
        int h0 = 2 * i + 9, w0 = 2 * j;
        size_t base = (size_t)bc * 1536 + tid;
        float o0r = __half2float(HSr[base + 0 * 256]), o0i = __half2float(HSi[base + 0 * 256]);
        float o1r = __half2float(HSr[base + 1 * 256]), o1i = __half2float(HSi[base + 1 * 256]);
        float o2r = __half2float(HSr[base + 2 * 256]), o2i = __half2float(HSi[base + 2 * 256]);
        float o3r = __half2float(HSr[base + 3 * 256]), o3i = __half2float(HSi[base + 3 * 256]);
        float o4r = __half2float(HSr[base + 4 * 256]), o4i = __half2float(HSi[base + 4 * 256]);
        float o5r = __half2float(HSr[base + 5 * 256]), o5i = __half2float(HSi[base + 5 * 256]);
        *(float2*)&slh[h0][w0] = make_float2((o0r + o5r) * ISQ2, (o0i + o5i) * ISQ2);
        *(float2*)&slh[h0 + 1][w0] = make_float2((o0i - o5i) * ISQ2, (o5r - o0r) * ISQ2);
        *(float2*)&shl[h0][w0] = make_float2((o2r + o3r) * ISQ2, (o2i + o3i) * ISQ2);
        *(float2*)&shl[h0 + 1][w0] = make_float2((o2i - o3i) * ISQ2, (o3r - o2r) * ISQ2);
        *(float2*)&shh[h0][w0] = make_float2((o1r + o4r) * ISQ2, (o1i + o4i) * ISQ2);
        *(float2*)&shh[h0 + 1][w0] = make_float2((o1i - o4i) * ISQ2, (o4r - o1r) * ISQ2);
    }
    __syncthreads();
    for (int i = tid; i < 576; i += 256) {
        int j = i >> 5, w = i & 31;
        int hp = (j < 9) ? (j - 9) : (23 + j);
        int hs = refl32(hp);
        sll[hp + 9][w] = sll[hs + 9][w];
        slh[hp + 9][w] = slh[hs + 9][w];
        shl[hp + 9][w] = shl[hs + 9][w];
        shh[hp + 9][w] = shh[hs + 9][w];
    }
    __syncthreads();
    {
        int wL = tid & 31, h0 = (tid >> 5) * 4;
        float w19[22], w13[16];
        float lo[4] = {0.f, 0.f, 0.f, 0.f}, hi[4] = {0.f, 0.f, 0.f, 0.f};
#pragma unroll
        for (int t = 0; t < 22; ++t) w19[t] = sll[h0 + t][wL];
#pragma unroll
        for (int k = 0; k < 19; ++k) {
            float g0 = (k & 1) ? H1c[k] : -H1c[k];
#pragma unroll
            for (int j = 0; j < 4; ++j) lo[j] += g0 * w19[j + k];
        }
#pragma unroll
        for (int t = 0; t < 16; ++t) w13[t] = slh[h0 + 3 + t][wL];
#pragma unroll
        for (int k = 0; k < 13; ++k) {
            float g1 = (k & 1) ? H0c[k] : -H0c[k];
#pragma unroll
            for (int j = 0; j < 4; ++j) lo[j] += g1 * w13[j + k];
        }
#pragma unroll
        for (int t = 0; t < 22; ++t) w19[t] = shl[h0 + t][wL];
#pragma unroll
        for (int k = 0; k < 19; ++k) {
            float g0 = (k & 1) ? H1c[k] : -H1c[k];
#pragma unroll
            for (int j = 0; j < 4; ++j) hi[j] += g0 * w19[j + k];
        }
#pragma unroll
        for (int t = 0; t < 16; ++t) w13[t] = shh[h0 + 3 + t][wL];
#pragma unroll
        for (int k = 0; k < 13; ++k) {
            float g1 = (k & 1) ? H0c[k] : -H0c[k];
#pragma unroll
            for (int j = 0; j < 4; ++j) hi[j] += g1 * w13[j + k];
        }
#pragma unroll
        for (int j = 0; j < 4; ++j) {
            slo[h0 + j][wL + 9] = lo[j];
            shi[h0 + j][wL + 9] = hi[j];
        }
    }
    __syncthreads();
    for (int i = tid; i < 576; i += 256) {
        int h = i / 18, j = i - (i / 18) * 18;
        int wp = (j < 9) ? (j - 9) : (23 + j);
        int ws2 = refl32(wp);
        slo[h][wp + 9] = slo[h][ws2 + 9];
        shi[h][wp + 9] = shi[h][ws2 + 9];
    }
    __syncthreads();
    {
        float rw[22], rh[16];
#pragma unroll
        for (int t = 0; t < 22; ++t) rw[t] = slo[hA][w0r + t];
#pragma unroll
        for (int t = 0; t < 16; ++t) rh[t] = shi[hA][w0r + 3 + t];
        float y[4] = {0.f, 0.f, 0.f, 0.f};
#pragma unroll
        for (int k = 0; k < 19; ++k) {
            float g0 = (k & 1) ? H1c[k] : -H1c[k];
#pragma unroll
            for (int j = 0; j < 4; ++j) y[j] += g0 * rw[j + k];
        }
#pragma unroll
        for (int k = 0; k < 13; ++k) {
            float g1 = (k & 1) ? H0c[k] : -H0c[k];
#pragma unroll
            for (int j = 0; j < 4; ++j) y[j] += g1 * rh[j + k];
        }
        __half2 y01 = __floats2half2_rn(y[0], y[1]);
        __half2 y23 = __floats2half2_rn(y[2], y[3]);
        uint2 pk;
        pk.x = *(unsigned int*)&y01;
        pk.y = *(unsigned int*)&y23;
        *(uint2*)(Yh + (size_t)bc * 1024 + hA * 32 + w0r) = pk;
    }
}

// ---------------- K4c: zero the halo of padded H1 (b,k0,34,34,32) fp16 --------
__global__ __launch_bounds__(256) void k_halo(__half2* __restrict__ H1h2) {
    int img = blockIdx.x;  // 2048
    __half2* base = H1h2 + (size_t)img * 1156 * 16;
    __half2 z = __floats2half2_rn(0.f, 0.f);
    for (int idx = threadIdx.x; idx < 2112; idx += 256) {
        int pos = idx >> 4, c = idx & 15;
        int p2;
        if (pos < 34) p2 = pos;
        else if (pos < 68) p2 = 33 * 34 + (pos - 34);
        else if (pos < 100) p2 = (pos - 68 + 1) * 34;
        else p2 = (pos - 100 + 1) * 34 + 33;
        base[p2 * 16 + c] = z;
    }
}

// ---------------- K4d: prep LeFF fp16 weight tables (runs AFTER k_inv) --------
__global__ __launch_bounds__(256) void k_prep_leff(const float* __restrict__ DW,
                                                   const float* __restrict__ DB,
                                                   const float* __restrict__ W2,
                                                   const float* __restrict__ W1,
                                                   __half2* __restrict__ DWh,
                                                   __half2* __restrict__ DBh,
                                                   __half* __restrict__ W2T,
                                                   __half* __restrict__ W1T) {
    int gid = blockIdx.x * 256 + threadIdx.x;
    int stride = gridDim.x * 256;
    for (int i = gid; i < 1152; i += stride) {
        int tap = i >> 7, pr = i & 127;
        DWh[i] = __floats2half2_rn(DW[(2 * pr) * 9 + tap], DW[(2 * pr + 1) * 9 + tap]);
    }
    for (int i = gid; i < 128; i += stride)
        DBh[i] = __floats2half2_rn(DB[2 * i], DB[2 * i + 1]);
    for (int i = gid; i < 16384; i += stride) {
        int n = i >> 8, k = i & 255;
        W2T[i] = __float2half(W2[k * 64 + n]);
    }
    for (int i = gid; i < 16384; i += stride)
        W1T[i] = __float2half(W1[(i & 63) * 256 + (i >> 6)]);
}

// ------ K5: fused (x + Y^T) residual + LN2 + lin1(MFMA) + GELU -> H1 ---------
// Yh tile staged through LDS (coalesced), transpose read from LDS.
__global__ __launch_bounds__(256) void k_leff1f(const float* __restrict__ x,
                                                const __half* __restrict__ Yh,
                                                const float* __restrict__ g2,
                                                const float* __restrict__ be2,
                                                const __half* __restrict__ W1T,
                                                const float* __restrict__ B1,
                                                float* __restrict__ out,
                                                __half* __restrict__ H1h) {
    __shared__ __half xnh[64][72];
    __shared__ __half syh[64][68];
    int tid = threadIdx.x;
    int wid = tid >> 6, lane = tid & 63;
    int lr = lane & 15, kg = lane >> 4;
    int bimg = blockIdx.x >> 4;
    int hw0 = (blockIdx.x & 15) << 6;
    size_t tok0 = (size_t)blockIdx.x * 64;
    int ltok = wid * 16 + lr;
    // --- stage Yh tile: 64 channels x 64 tokens fp16, fully coalesced ---
    {
        int c = tid >> 2;
        int t0 = (tid & 3) * 16;
        const uint4* yp4 = (const uint4*)(Yh + ((size_t)bimg * 64 + c) * 1024 + hw0 + t0);
        uint4 a = yp4[0], b = yp4[1];
        *(uint4*)&syh[c][t0] = a;
        *(uint4*)&syh[c][t0 + 8] = b;
    }
    __syncthreads();
    {
        const float4* xp = (const float4*)(x + (tok0 + ltok) * 64 + kg * 16);
        float4 v0 = xp[0], v1 = xp[1], v2 = xp[2], v3 = xp[3];
        float yv[16];
#pragma unroll
        for (int i = 0; i < 16; ++i) yv[i] = __half2float(syh[kg * 16 + i][ltok]);
        v0.x += yv[0]; v0.y += yv[1]; v0.z += yv[2]; v0.w += yv[3];
        v1.x += yv[4]; v1.y += yv[5]; v1.z += yv[6]; v1.w += yv[7];
        v2.x += yv[8]; v2.y += yv[9]; v2.z += yv[10]; v2.w += yv[11];
        v3.x += yv[12]; v3.y += yv[13]; v3.z += yv[14]; v3.w += yv[15];
        float4* op = (float4*)(out + (tok0 + ltok) * 64 + kg * 16);
        op[0] = v0; op[1] = v1; op[2] = v2; op[3] = v3;
        float s = v0.x + v0.y + v0.z + v0.w + v1.x + v1.y + v1.z + v1.w +
                  v2.x + v2.y + v2.z + v2.w + v3.x + v3.y + v3.z + v3.w;
        float ss = v0.x * v0.x + v0.y * v0.y + v0.z * v0.z + v0.w * v0.w +
                   v1.x * v1.x + v1.y * v1.y + v1.z * v1.z + v1.w * v1.w +
                   v2.x * v2.x + v2.y * v2.y + v2.z * v2.z + v2.w * v2.w +
                   v3.x * v3.x + v3.y * v3.y + v3.z * v3.z + v3.w * v3.w;
        s += __shfl_xor(s, 16, 64);
        ss += __shfl_xor(ss, 16, 64);
        s += __shfl_xor(s, 32, 64);
        ss += __shfl_xor(ss, 32, 64);
        float m = s * (1.f / 64.f);
        float var = ss * (1.f / 64.f) - m * m;
        float rstd = rsqrtf(var + 1e-5f);
        float vv[16] = {v0.x, v0.y, v0.z, v0.w, v1.x, v1.y, v1.z, v1.w,
                        v2.x, v2.y, v2.z, v2.w, v3.x, v3.y, v3.z, v3.w};
        unsigned int u[8];
#pragma unroll
        for (int i = 0; i < 8; ++i) {
            int d = kg * 16 + 2 * i;
            float a0 = (vv[2 * i] - m) * rstd * g2[d] + be2[d];
            float a1 = (vv[2 * i + 1] - m) * rstd * g2[d + 1] + be2[d + 1];
            __half2 hh = __floats2half2_rn(a0, a1);
            u[i] = *(unsigned int*)&hh;
        }
        *(uint4*)&xnh[ltok][kg * 16] = make_uint4(u[0], u[1], u[2], u[3]);
        *(uint4*)&xnh[ltok][kg * 16 + 8] = make_uint4(u[4], u[5], u[6], u[7]);
    }
    __syncthreads();
    f32x4 acc[16];
#pragma unroll
    for (int n = 0; n < 16; ++n) acc[n] = (f32x4){0.f, 0.f, 0.f, 0.f};
#pragma unroll
    for (int k0 = 0; k0 < 2; ++k0) {
        f16x8 a = *(const f16x8*)&xnh[wid * 16 + lr][k0 * 32 + kg * 8];
#pragma unroll
        for (int n = 0; n < 16; ++n) {
            f16x8 bf = *(const f16x8*)(W1T + (size_t)(n * 16 + lr) * 64 + k0 * 32 + kg * 8);
            acc[n] = __builtin_amdgcn_mfma_f32_16x16x32_f16(a, bf, acc[n], 0, 0, 0);
        }
    }
#pragma unroll
    for (int n = 0; n < 16; ++n) {
        int hid = n * 16 + lr;
        float bb = B1[hid];
        size_t cb = ((size_t)bimg * 8 + (hid >> 5)) * 1156;
        int cl = hid & 31;
#pragma unroll
        for (int reg = 0; reg < 4; ++reg) {
            int token = wid * 16 + kg * 4 + reg;
            int hw = hw0 + token;
            int h = hw >> 5, w = hw & 31;
            H1h[(cb + (size_t)(h + 1) * 34 + (w + 1)) * 32 + cl] =
                __float2half(gelu_fast(acc[n][reg] + bb));
        }
    }
}

// ---------------- K6: fused dwconv+GELU+lin2(MFMA), 2 rows/wave ---------------
struct Tap12 { uint4 v[12]; };

__device__ __forceinline__ void load12(const __half* H1h, size_t pb, int kg, Tap12& T) {
    const __half2* p = (const __half2*)(H1h + pb * 32) + kg * 4;
#pragma unroll
    for (int r = 0; r < 4; ++r)
#pragma unroll
        for (int dc = 0; dc < 3; ++dc)
            T.v[r * 3 + dc] = *(const uint4*)(p + ((r - 1) * 34 + (dc - 1)) * 16);
}

__device__ __forceinline__ void convg2(const Tap12& T,
                                       const __half2* __restrict__ DBh,
                                       const __half2* __restrict__ DWh,
                                       int k0, int kg, f16x8& a0out, f16x8& a1out) {
    const __half2* dbp = DBh + k0 * 16 + kg * 4;
    __half2 c00 = dbp[0], c01 = dbp[1], c02 = dbp[2], c03 = dbp[3];
    __half2 c10 = c00, c11 = c01, c12 = c02, c13 = c03;
#pragma unroll
    for (int dr = 0; dr < 3; ++dr) {
#pragma unroll
        for (int dc = 0; dc < 3; ++dc) {
            const __half2* wp = DWh + (dr * 3 + dc) * 128 + k0 * 16 + kg * 4;
            __half2 w0 = wp[0], w1 = wp[1], w2 = wp[2], w3 = wp[3];
            const uint4& t0 = T.v[dr * 3 + dc];
            const uint4& t1 = T.v[(dr + 1) * 3 + dc];
            c00 = __hfma2(u2h2(t0.x), w0, c00);
            c01 = __hfma2(u2h2(t0.y), w1, c01);
            c02 = __hfma2(u2h2(t0.z), w2, c02);
            c03 = __hfma2(u2h2(t0.w), w3, c03);
            c10 = __hfma2(u2h2(t1.x), w0, c10);
            c11 = __hfma2(u2h2(t1.y), w1, c11);
            c12 = __hfma2(u2h2(t1.z), w2, c12);
            c13 = __hfma2(u2h2(t1.w), w3, c13);
        }
    }
    __half2 o0 = __floats2half2_rn(gelu_fast(__low2float(c00)), gelu_fast(__high2float(c00)));
    __half2 o1 = __floats2half2_rn(gelu_fast(__low2float(c01)), gelu_fast(__high2float(c01)));
    __half2 o2 = __floats2half2_rn(gelu_fast(__low2float(c02)), gelu_fast(__high2float(c02)));
    __half2 o3 = __floats2half2_rn(gelu_fast(__low2float(c03)), gelu_fast(__high2float(c03)));
    uint4 av0 = make_uint4(*(unsigned int*)&o0, *(unsigned int*)&o1,
                           *(unsigned int*)&o2, *(unsigned int*)&o3);
    a0out = *(f16x8*)&av0;
    o0 = __floats2half2_rn(gelu_fast(__low2float(c10)), gelu_fast(__high2float(c10)));
    o1 = __floats2half2_rn(gelu_fast(__low2float(c11)), gelu_fast(__high2float(c11)));
    o2 = __floats2half2_rn(gelu_fast(__low2float(c12)), gelu_fast(__high2float(c12)));
    o3 = __floats2half2_rn(gelu_fast(__low2float(c13)), gelu_fast(__high2float(c13)));
    uint4 av1 = make_uint4(*(unsigned int*)&o0, *(unsigned int*)&o1,
                           *(unsigned int*)&o2, *(unsigned int*)&o3);
    a1out = *(f16x8*)&av1;
}

__global__ __launch_bounds__(256, 3) void k_leff2m(const __half* __restrict__ H1h,
                                                   const __half2* __restrict__ DWh,
                                                   const __half2* __restrict__ DBh,
                                                   const __half* __restrict__ W2T,
                                                   const float* __restrict__ B2,
                                                   float* __restrict__ out) {
    int tid = threadIdx.x;
    int wid = tid >> 6, lane = tid & 63;
    int mt = blockIdx.x * 4 + wid;   // 0..8191
    int b = mt >> 5;
    int rem = mt & 31;
    int h0 = (rem >> 1) * 2;
    int w0 = (rem & 1) << 4;
    int lr = lane & 15, kg = lane >> 4;
    int wA = w0 + lr;

    f32x4 acc0[4], acc1[4];
#pragma unroll
    for (int n = 0; n < 4; ++n) {
        acc0[n] = (f32x4){0.f, 0.f, 0.f, 0.f};
        acc1[n] = (f32x4){0.f, 0.f, 0.f, 0.f};
    }

    size_t rowoff = (size_t)h0 * 34 + wA;
    Tap12 TA, TB;
    load12(H1h, ((size_t)b * 8 + 0) * 1156 + rowoff + 35, kg, TA);
#pragma unroll
    for (int k0 = 0; k0 < 8; ++k0) {
        if (k0 < 7)
            load12(H1h, ((size_t)b * 8 + (k0 + 1)) * 1156 + rowoff + 35, kg,
                   (k0 & 1) ? TA : TB);
        f16x8 a0, a1;
        convg2((k0 & 1) ? TB : TA, DBh, DWh, k0, kg, a0, a1);
#pragma unroll
        for (int n = 0; n < 4; ++n) {
            f16x8 bf = *(const f16x8*)(W2T + ((size_t)(n * 16 + lr) * 256 + k0 * 32 + kg * 8));
            acc0[n] = __builtin_amdgcn_mfma_f32_16x16x32_f16(a0, bf, acc0[n], 0, 0, 0);
            acc1[n] = __builtin_amdgcn_mfma_f32_16x16x32_f16(a1, bf, acc1[n], 0, 0, 0);
        }
    }
    size_t ob0 = (size_t)b * 1024 + (size_t)h0 * 32;
#pragma unroll
    for (int n = 0; n < 4; ++n) {
        int c = n * 16 + lr;
        float b2v = B2[c];
#pragma unroll
        for (int reg = 0; reg < 4; ++reg) {
            int rowTok = w0 + kg * 4 + reg;
            size_t g0i = (ob0 + rowTok) * 64 + c;
            out[g0i] += acc0[n][reg] + b2v;
            size_t g1i = (ob0 + 32 + rowTok) * 64 + c;
            out[g1i] += acc1[n][reg] + b2v;
        }
    }
}

extern "C" void kernel_launch(void* const* d_in, const int* in_sizes, int n_in,
                              void* d_out, int out_size, void* d_ws, size_t ws_size,
                              hipStream_t stream) {
    const float* x = (const float*)d_in[0];
    const float* ln1_g = (const float*)d_in[1];
    const float* ln1_b = (const float*)d_in[2];
    const float* w_ll = (const float*)d_in[3];
    const float* w1 = (const float*)d_in[4];
    const float* w2 = (const float*)d_in[5];
    const float* b1 = (const float*)d_in[6];
    const float* b2 = (const float*)d_in[7];
    const float* ln2_g = (const float*)d_in[8];
    const float* ln2_b = (const float*)d_in[9];
    const float* lin1_w = (const float*)d_in[10];
    const float* lin1_b = (const float*)d_in[11];
    const float* dw_w = (const float*)d_in[12];
    const float* dw_b = (const float*)d_in[13];
    const float* lin2_w = (const float*)d_in[14];
    const float* lin2_b = (const float*)d_in[15];
    float* out = (float*)d_out;
    char* ws = (char*)d_ws;

    // Lifetimes:
    //  Ah   [0, 33.5MB)        : LN1 out; dead after k_fwd. Reused: mlp tables, H1h.
    //  HSr  [64MiB, 112MiB)    : live k_fwd..k_inv.
    //  HSi  [160MiB, 208MiB)   : live k_fwd..k_inv. Reused after inv: leff tables.
    //  Yh   [208MiB, 240MiB)   : written by k_inv, read by k_leff1f.
    //  H1h  [0, 144.5MiB)      : k_halo/k_leff1f write, k_leff2m reads.
    __half* Ah = (__half*)ws;
    __half* HSr = (__half*)(ws + 67108864);
    __half* HSi = (__half*)(ws + 167772160);
    float* LL = out;
    __half* Yh = (__half*)(ws + 218103808);   // 208 MiB
    __half* H1h = (__half*)ws;
    __half* W1cr = (__half*)(ws);
    __half* W1ci = (__half*)(ws + 4096);
    __half* W2cr = (__half*)(ws + 8192);
    __half* W2ci = (__half*)(ws + 12288);
    char* wtab = ws + 167772160;
    __half2* DWh = (__half2*)(wtab);
    __half2* DBh = (__half2*)(wtab + 8192);
    __half* W2T = (__half*)(wtab + 12288);
    __half* W1T = (__half*)(wtab + 49152);

    k_ln1_t<<<dim3(4096), dim3(256), 0, stream>>>(x, ln1_g, ln1_b, Ah);
    k_fwd<<<dim3(16384), dim3(256), 0, stream>>>(Ah, w_ll, LL, HSr, HSi);
    k_prep_mlp<<<dim3(8), dim3(256), 0, stream>>>(w1, w2, W1cr, W1ci, W2cr, W2ci);
    k_mlpm<<<dim3(1536), dim3(256), 0, stream>>>(HSr, HSi, W1cr, W1ci, W2cr, W2ci, b1, b2);
    k_inv<<<dim3(16384), dim3(256), 0, stream>>>(LL, HSr, HSi, Yh);
    k_halo<<<dim3(2048), dim3(256), 0, stream>>>((__half2*)H1h);
    k_prep_leff<<<dim3(72), dim3(256), 0, stream>>>(dw_w, dw_b, lin2_w, lin1_w,
                                                    DWh, DBh, W2T, W1T);
    k_leff1f<<<dim3(4096), dim3(256), 0, stream>>>(x, Yh, ln2_g, ln2_b, W1T, lin1_b,
                                                   out, H1h);
    k_leff2m<<<dim3(2048), dim3(256), 0, stream>>>(H1h, DWh, DBh, W2T, b2, out);
}

// Round 20
// 471.949 us; speedup vs baseline: 1.0436x; 1.0436x over previous
//
#include <hip/hip_runtime.h>
#include <hip/hip_fp16.h>
#include <math.h>

#define ISQ2 0.70710678118654752440f

typedef _Float16 f16x8 __attribute__((ext_vector_type(8)));
typedef __attribute__((ext_vector_type(4))) float f32x4;

static __device__ __constant__ float H0c[13] = {
    -0.0017578f, 0.0f, 0.0222656f, -0.046875f, -0.0482422f, 0.296875f,
    0.5554688f, 0.296875f, -0.0482422f, -0.046875f, 0.0222656f, 0.0f, -0.0017578f};
static __device__ __constant__ float H1c[19] = {
    -7.06e-05f, 0.0f, 0.0013419f, -0.0018834f, -0.0071568f, 0.023856f,
    0.0556431f, -0.0516881f, -0.2997576f, 0.5594308f, -0.2997576f, -0.0516881f,
    0.0556431f, 0.023856f, -0.0071568f, -0.0018834f, 0.0013419f, 0.0f, -7.06e-05f};

__device__ __forceinline__ int refl32(int i) {
    if (i < 0) i = -1 - i;
    if (i > 31) i = 63 - i;
    return i;
}

// tanh-form GELU: |err| < ~1e-3 vs exact erf form
__device__ __forceinline__ float gelu_fast(float x) {
    float u = x * (0.7978845608f + 0.0356774081f * x * x);
    float e = __expf(-2.0f * fabsf(u));
    float t = 1.0f - 2.0f * e / (1.0f + e);
    t = copysignf(t, u);
    return 0.5f * x * (1.0f + t);
}

__device__ __forceinline__ __half2 u2h2(unsigned int u) {
    union { unsigned int u; __half2 h; } c;
    c.u = u;
    return c.h;
}

// ---------------- K1: LN1 + transpose (B,N,C)->(B,C,32,32) fp16 --------------
__global__ __launch_bounds__(256) void k_ln1_t(const float* __restrict__ x,
                                               const float* __restrict__ g,
                                               const float* __restrict__ be,
                                               __half* __restrict__ Ah) {
    __shared__ float sx[64][65];
    __shared__ float rs[64][4], rq[64][4];
    __shared__ float sm[64], sv[64];
    int b = blockIdx.x >> 4;
    int n0 = (blockIdx.x & 15) << 6;
    int tid = threadIdx.x;
    const float* xp = x + ((size_t)b * 1024 + n0) * 64;
#pragma unroll
    for (int rep = 0; rep < 16; ++rep) {
        int idx = rep * 256 + tid;
        sx[idx >> 6][idx & 63] = xp[idx];
    }
    __syncthreads();
    {
        int i = tid >> 2, q = tid & 3;
        float s = 0.f, ss = 0.f;
#pragma unroll
        for (int d = 0; d < 16; ++d) {
            float v = sx[i][q * 16 + d];
            s += v; ss += v * v;
        }
        rs[i][q] = s; rq[i][q] = ss;
    }
    __syncthreads();
    if (tid < 64) {
        float s = rs[tid][0] + rs[tid][1] + rs[tid][2] + rs[tid][3];
        float ss = rq[tid][0] + rq[tid][1] + rq[tid][2] + rq[tid][3];
        float m = s * (1.f / 64.f);
        float v = ss * (1.f / 64.f) - m * m;
        sm[tid] = m;
        sv[tid] = rsqrtf(v + 1e-5f);
    }
    __syncthreads();
#pragma unroll
    for (int rep = 0; rep < 16; ++rep) {
        int idx = rep * 256 + tid;
        int c = idx >> 6, i = idx & 63;
        float val = (sx[i][c] - sm[i]) * sv[i] * g[c] + be[c];
        Ah[((size_t)(b * 64 + c)) * 1024 + n0 + i] = __float2half(val);
    }
}

// ---------------- K2: forward DTCWT (fp16 in/out), sliding windows ------------
__global__ __launch_bounds__(256, 4) void k_fwd(const __half* __restrict__ Ah,
                                                const float* __restrict__ wll,
                                                float* __restrict__ LL,
                                                __half* __restrict__ HSr,
                                                __half* __restrict__ HSi) {
    __shared__ float sx[32][52];
    __shared__ float slo[50][34];
    __shared__ float shi[50][34];
    int bc = blockIdx.x;
    int c = bc & 63;
    int tid = threadIdx.x;
    int hA = tid >> 3, w0r = (tid & 7) * 4;
    {
        const __half2* ap2 = (const __half2*)(Ah + (size_t)bc * 1024);
        __half2 v01 = ap2[tid * 2], v23 = ap2[tid * 2 + 1];
        sx[hA][w0r + 9] = __low2float(v01);
        sx[hA][w0r + 10] = __high2float(v01);
        sx[hA][w0r + 11] = __low2float(v23);
        sx[hA][w0r + 12] = __high2float(v23);
    }
    __syncthreads();
    for (int i = tid; i < 576; i += 256) {
        int h = i / 18, j = i - (i / 18) * 18;
        int wp = (j < 9) ? (j - 9) : (23 + j);
        sx[h][wp + 9] = sx[h][refl32(wp) + 9];
    }
    __syncthreads();
    {
        float ws[22];
#pragma unroll
        for (int t = 0; t < 22; ++t) ws[t] = sx[hA][w0r + t];
        float lo[4] = {0.f, 0.f, 0.f, 0.f}, hi[4] = {0.f, 0.f, 0.f, 0.f};
#pragma unroll
        for (int k = 0; k < 19; ++k)
#pragma unroll
            for (int j = 0; j < 4; ++j) hi[j] += H1c[k] * ws[j + k];
#pragma unroll
        for (int k = 0; k < 13; ++k)
#pragma unroll
            for (int j = 0; j < 4; ++j) lo[j] += H0c[k] * ws[j + k + 3];
#pragma unroll
        for (int j = 0; j < 4; ++j) {
            slo[hA + 9][w0r + j] = lo[j];
            shi[hA + 9][w0r + j] = hi[j];
        }
    }
    __syncthreads();
    for (int i = tid; i < 576; i += 256) {
        int j = i >> 5, w = i & 31;
        int hp = (j < 9) ? (j - 9) : (23 + j);
        int hs = refl32(hp);
        slo[hp + 9][w] = slo[hs + 9][w];
        shi[hp + 9][w] = shi[hs + 9][w];
    }
    __syncthreads();
    {
        int wL = tid & 31, h0 = (tid >> 5) * 4;
        float cs[16];
#pragma unroll
        for (int t = 0; t < 16; ++t) cs[t] = slo[h0 + 3 + t][wL];
#pragma unroll
        for (int j = 0; j < 4; ++j) {
            float acc = 0.f;
#pragma unroll
            for (int k = 0; k < 13; ++k) acc += H0c[k] * cs[j + k];
            int p = (h0 + j) * 32 + wL;
            LL[(size_t)bc * 1024 + p] = acc * wll[c * 1024 + p];
        }
    }
    {
        int i = tid >> 4, j = tid & 15;
        size_t base = (size_t)bc * 1536 + tid;
        float a, bb, cc2, dd;
        {
            float2 sl[20];
#pragma unroll
            for (int t = 0; t < 20; ++t) sl[t] = *(const float2*)&slo[2 * i + t][2 * j];
            a = bb = cc2 = dd = 0.f;
#pragma unroll
            for (int k = 0; k < 19; ++k) {
                a += H1c[k] * sl[k].x;
                bb += H1c[k] * sl[k].y;
                cc2 += H1c[k] * sl[k + 1].x;
                dd += H1c[k] * sl[k + 1].y;
            }
            HSr[base + 0 * 256] = __float2half((a - dd) * ISQ2);
            HSi[base + 0 * 256] = __float2half((bb + cc2) * ISQ2);
            HSr[base + 5 * 256] = __float2half((a + dd) * ISQ2);
            HSi[base + 5 * 256] = __float2half((bb - cc2) * ISQ2);
        }
        {
            float2 sh[20];
#pragma unroll
            for (int t = 0; t < 20; ++t) sh[t] = *(const float2*)&shi[2 * i + t][2 * j];
            a = bb = cc2 = dd = 0.f;
#pragma unroll
            for (int k = 0; k < 19; ++k) {
                a += H1c[k] * sh[k].x;
                bb += H1c[k] * sh[k].y;
                cc2 += H1c[k] * sh[k + 1].x;
                dd += H1c[k] * sh[k + 1].y;
            }
            HSr[base + 1 * 256] = __float2half((a - dd) * ISQ2);
            HSi[base + 1 * 256] = __float2half((bb + cc2) * ISQ2);
            HSr[base + 4 * 256] = __float2half((a + dd) * ISQ2);
            HSi[base + 4 * 256] = __float2half((bb - cc2) * ISQ2);
            a = bb = cc2 = dd = 0.f;
#pragma unroll
            for (int k = 0; k < 13; ++k) {
                a += H0c[k] * sh[k + 3].x;
                bb += H0c[k] * sh[k + 3].y;
                cc2 += H0c[k] * sh[k + 4].x;
                dd += H0c[k] * sh[k + 4].y;
            }
            HSr[base + 2 * 256] = __float2half((a - dd) * ISQ2);
            HSi[base + 2 * 256] = __float2half((bb + cc2) * ISQ2);
            HSr[base + 3 * 256] = __float2half((a + dd) * ISQ2);
            HSi[base + 3 * 256] = __float2half((bb - cc2) * ISQ2);
        }
    }
}

// ---------------- K2b: prep complex-MLP fp16 B-frags (runs AFTER k_fwd) -------
__global__ __launch_bounds__(256) void k_prep_mlp(const float* __restrict__ mw1,
                                                  const float* __restrict__ mw2,
                                                  __half* __restrict__ W1cr,
                                                  __half* __restrict__ W1ci,
                                                  __half* __restrict__ W2cr,
                                                  __half* __restrict__ W2ci) {
    int gid = blockIdx.x * 256 + threadIdx.x;
    int stride = gridDim.x * 256;
    for (int i = gid; i < 2048; i += stride) {
        int q = i >> 9, rest = i & 511;
        int n = rest >> 5, k = rest & 31;
        if (k < 16) {
            W1cr[i] = __float2half(mw1[q * 256 + k * 16 + n]);
            W1ci[i] = __float2half(mw1[1024 + q * 256 + k * 16 + n]);
            W2cr[i] = __float2half(mw2[q * 256 + k * 16 + n]);
            W2ci[i] = __float2half(mw2[1024 + q * 256 + k * 16 + n]);
        } else {
            W1cr[i] = __float2half(-mw1[1024 + q * 256 + (k - 16) * 16 + n]);
            W1ci[i] = __float2half(mw1[q * 256 + (k - 16) * 16 + n]);
            W2cr[i] = __float2half(-mw2[1024 + q * 256 + (k - 16) * 16 + n]);
            W2ci[i] = __float2half(mw2[q * 256 + (k - 16) * 16 + n]);
        }
    }
}

// ---------------- K3: complex block-MLP via MFMA, fp16 HS in/out --------------
__global__ __launch_bounds__(256) void k_mlpm(__half* __restrict__ HSr,
                                              __half* __restrict__ HSi,
                                              const __half* __restrict__ W1cr,
                                              const __half* __restrict__ W1ci,
                                              const __half* __restrict__ W2cr,
                                              const __half* __restrict__ W2ci,
                                              const float* __restrict__ b1,
                                              const float* __restrict__ b2) {
    __shared__ __half xh[4][64][40];
    int tid = threadIdx.x;
    int wid = tid >> 6, lane = tid & 63;
    int lr = lane & 15, kg = lane >> 4;
    int b = blockIdx.x / 6;
    int o = blockIdx.x - b * 6;
    size_t base = (size_t)b * 98304 + (size_t)o * 256;

#pragma unroll 1
    for (int q = 0; q < 4; ++q) {
#pragma unroll
        for (int mt = 0; mt < 4; ++mt) {
            int token0 = wid * 64 + mt * 16;
            const unsigned short* src =
                (const unsigned short*)((kg < 2) ? HSr : HSi);
            int c0 = q * 16 + (kg & 1) * 8;
            unsigned int u[4];
#pragma unroll
            for (int e = 0; e < 4; ++e) {
                unsigned int lo = src[base + (size_t)(c0 + 2 * e) * 1536 + token0 + lr];
                unsigned int hi = src[base + (size_t)(c0 + 2 * e + 1) * 1536 + token0 + lr];
                u[e] = lo | (hi << 16);
            }
            uint4 av = make_uint4(u[0], u[1], u[2], u[3]);
            f16x8 a = *(f16x8*)&av;
            f16x8 bfr = *(const f16x8*)(W1cr + q * 512 + lr * 32 + kg * 8);
            f16x8 bfi = *(const f16x8*)(W1ci + q * 512 + lr * 32 + kg * 8);
            f32x4 accr = (f32x4){0.f, 0.f, 0.f, 0.f};
            f32x4 acci = (f32x4){0.f, 0.f, 0.f, 0.f};
            accr = __builtin_amdgcn_mfma_f32_16x16x32_f16(a, bfr, accr, 0, 0, 0);
            acci = __builtin_amdgcn_mfma_f32_16x16x32_f16(a, bfi, acci, 0, 0, 0);
            float b1r = b1[q * 16 + lr];
            float b1i = b1[64 + q * 16 + lr];
#pragma unroll
            for (int reg = 0; reg < 4; ++reg) {
                int tl = mt * 16 + kg * 4 + reg;
                xh[wid][tl][lr] = __float2half(fmaxf(accr[reg] + b1r, 0.f));
                xh[wid][tl][16 + lr] = __float2half(fmaxf(acci[reg] + b1i, 0.f));
            }
        }
        __syncthreads();
#pragma unroll
        for (int mt = 0; mt < 4; ++mt) {
            f16x8 a = *(const f16x8*)&xh[wid][mt * 16 + lr][kg * 8];
            f16x8 bfr = *(const f16x8*)(W2cr + q * 512 + lr * 32 + kg * 8);
            f16x8 bfi = *(const f16x8*)(W2ci + q * 512 + lr * 32 + kg * 8);
            f32x4 accr = (f32x4){0.f, 0.f, 0.f, 0.f};
            f32x4 acci = (f32x4){0.f, 0.f, 0.f, 0.f};
            accr = __builtin_amdgcn_mfma_f32_16x16x32_f16(a, bfr, accr, 0, 0, 0);
            acci = __builtin_amdgcn_mfma_f32_16x16x32_f16(a, bfi, acci, 0, 0, 0);
            float b2r = b2[q * 16 + lr];
            float b2i = b2[64 + q * 16 + lr];
            size_t cb = base + (size_t)(q * 16 + lr) * 1536 + wid * 64 + mt * 16 + kg * 4;
#pragma unroll
            for (int reg = 0; reg < 4; ++reg) {
                HSr[cb + reg] = __float2half(accr[reg] + b2r);
                HSi[cb + reg] = __float2half(acci[reg] + b2i);
            }
        }
        __syncthreads();
    }
}

// ---------------- K4: inverse DTCWT (fp16 in/out), sliding windows ------------
__global__ __launch_bounds__(256, 4) void k_inv(const float* __restrict__ LL,
                                                const __half* __restrict__ HSr,
                                                const __half* __restrict__ HSi,
                                                __half* __restrict__ Yh) {
    __shared__ float sll[50][34], slh[50][34], shl[50][34], shh[50][34];
    __shared__ float slo[32][52], shi[32][52];
    int bc = blockIdx.x;
    int tid = threadIdx.x;
    int hA = tid >> 3, w0r = (tid & 7) * 4;
    {
        const float4* lp4 = (const float4*)(LL + (size_t)bc * 1024);
        float4 v = lp4[tid];
        sll[hA + 9][w0r] = v.x;
        sll[hA + 9][w0r + 1] = v.y;
        sll[hA + 9][w0r + 2] = v.z;
        sll[hA + 9][w0r + 3] = v.w;
    }
    {
        int i = tid >> 4, j = tid & 15;
        int h0 = 2 * i + 9, w0 = 2 * j;
        size_t base = (size_t)bc * 1536 + tid;
        float o0r = __half2float(HSr[base + 0 * 256]), o0i = __half2float(HSi[base + 0 * 256]);
        float o1r = __half2float(HSr[base + 1 * 256]), o1i = __half2float(HSi[base + 1 * 256]);
        float o2r = __half2float(HSr[base + 2 * 256]), o2i = __half2float(HSi[base + 2 * 256]);
        float o3r = __half2float(HSr[base + 3 * 256]), o3i = __half2float(HSi[base + 3 * 256]);
        float o4r = __half2float(HSr[base + 4 * 256]), o4i = __half2float(HSi[base + 4 * 256]);
        float o5r = __half2float(HSr[base + 5 * 256]), o5i = __half2float(HSi[base + 5 * 256]);
        *(float2*)&slh[h0][w0] = make_float2((o0r + o5r) * ISQ2, (o0i + o5i) * ISQ2);
        *(float2*)&slh[h0 + 1][w0] = make_float2((o0i - o5i) * ISQ2, (o5r - o0r) * ISQ2);
        *(float2*)&shl[h0][w0] = make_float2((o2r + o3r) * ISQ2, (o2i + o3i) * ISQ2);
        *(float2*)&shl[h0 + 1][w0] = make_float2((o2i - o3i) * ISQ2, (o3r - o2r) * ISQ2);
        *(float2*)&shh[h0][w0] = make_float2((o1r + o4r) * ISQ2, (o1i + o4i) * ISQ2);
        *(float2*)&shh[h0 + 1][w0] = make_float2((o1i - o4i) * ISQ2, (o4r - o1r) * ISQ2);
    }
    __syncthreads();
    for (int i = tid; i < 576; i += 256) {
        int j = i >> 5, w = i & 31;
        int hp = (j < 9) ? (j - 9) : (23 + j);
        int hs = refl32(hp);
        sll[hp + 9][w] = sll[hs + 9][w];
        slh[hp + 9][w] = slh[hs + 9][w];
        shl[hp + 9][w] = shl[hs + 9][w];
        shh[hp + 9][w] = shh[hs + 9][w];
    }
    __syncthreads();
    {
        int wL = tid & 31, h0 = (tid >> 5) * 4;
        float w19[22], w13[16];
        float lo[4] = {0.f, 0.f, 0.f, 0.f}, hi[4] = {0.f, 0.f, 0.f, 0.f};
#pragma unroll
        for (int t = 0; t < 22; ++t) w19[t] = sll[h0 + t][wL];
#pragma unroll
        for (int k = 0; k < 19; ++k) {
            float g0 = (k & 1) ? H1c[k] : -H1c[k];
#pragma unroll
            for (int j = 0; j < 4; ++j) lo[j] += g0 * w19[j + k];
        }
#pragma unroll
        for (int t = 0; t < 16; ++t) w13[t] = slh[h0 + 3 + t][wL];
#pragma unroll
        for (int k = 0; k < 13; ++k) {
            float g1 = (k & 1) ? H0c[k] : -H0c[k];
#pragma unroll
            for (int j = 0; j < 4; ++j) lo[j] += g1 * w13[j + k];
        }
#pragma unroll
        for (int t = 0; t < 22; ++t) w19[t] = shl[h0 + t][wL];
#pragma unroll
        for (int k = 0; k < 19; ++k) {
            float g0 = (k & 1) ? H1c[k] : -H1c[k];
#pragma unroll
            for (int j = 0; j < 4; ++j) hi[j] += g0 * w19[j + k];
        }
#pragma unroll
        for (int t = 0; t < 16; ++t) w13[t] = shh[h0 + 3 + t][wL];
#pragma unroll
        for (int k = 0; k < 13; ++k) {
            float g1 = (k & 1) ? H0c[k] : -H0c[k];
#pragma unroll
            for (int j = 0; j < 4; ++j) hi[j] += g1 * w13[j + k];
        }
#pragma unroll
        for (int j = 0; j < 4; ++j) {
            slo[h0 + j][wL + 9] = lo[j];
            shi[h0 + j][wL + 9] = hi[j];
        }
    }
    __syncthreads();
    for (int i = tid; i < 576; i += 256) {
        int h = i / 18, j = i - (i / 18) * 18;
        int wp = (j < 9) ? (j - 9) : (23 + j);
        int ws2 = refl32(wp);
        slo[h][wp + 9] = slo[h][ws2 + 9];
        shi[h][wp + 9] = shi[h][ws2 + 9];
    }
    __syncthreads();
    {
        float rw[22], rh[16];
#pragma unroll
        for (int t = 0; t < 22; ++t) rw[t] = slo[hA][w0r + t];
#pragma unroll
        for (int t = 0; t < 16; ++t) rh[t] = shi[hA][w0r + 3 + t];
        float y[4] = {0.f, 0.f, 0.f, 0.f};
#pragma unroll
        for (int k = 0; k < 19; ++k) {
            float g0 = (k & 1) ? H1c[k] : -H1c[k];
#pragma unroll
            for (int j = 0; j < 4; ++j) y[j] += g0 * rw[j + k];
        }
#pragma unroll
        for (int k = 0; k < 13; ++k) {
            float g1 = (k & 1) ? H0c[k] : -H0c[k];
#pragma unroll
            for (int j = 0; j < 4; ++j) y[j] += g1 * rh[j + k];
        }
        __half2 y01 = __floats2half2_rn(y[0], y[1]);
        __half2 y23 = __floats2half2_rn(y[2], y[3]);
        uint2 pk;
        pk.x = *(unsigned int*)&y01;
        pk.y = *(unsigned int*)&y23;
        *(uint2*)(Yh + (size_t)bc * 1024 + hA * 32 + w0r) = pk;
    }
}

// ---------------- K4b: X1 = x + Y^T -> d_out (B,N,C) ----------------
__global__ __launch_bounds__(256) void k_addt(const __half* __restrict__ Yh,
                                              const float* __restrict__ x,
                                              float* __restrict__ out) {
    __shared__ float sy[64][65];
    int b = blockIdx.x >> 4;
    int n0 = (blockIdx.x & 15) << 6;
    int tid = threadIdx.x;
#pragma unroll
    for (int rep = 0; rep < 16; ++rep) {
        int idx = rep * 256 + tid;
        int c = idx >> 6, i = idx & 63;
        sy[c][i] = __half2float(Yh[((size_t)(b * 64 + c)) * 1024 + n0 + i]);
    }
    __syncthreads();
#pragma unroll
    for (int rep = 0; rep < 16; ++rep) {
        int idx = rep * 256 + tid;
        int i = idx >> 6, c = idx & 63;
        size_t gi = ((size_t)b * 1024 + n0 + i) * 64 + c;
        out[gi] = x[gi] + sy[c][i];
    }
}

// ---------------- K4c: zero the halo of padded H1 (b,k0,34,34,32) fp16 --------
__global__ __launch_bounds__(256) void k_halo(__half2* __restrict__ H1h2) {
    int img = blockIdx.x;  // 2048
    __half2* base = H1h2 + (size_t)img * 1156 * 16;
    __half2 z = __floats2half2_rn(0.f, 0.f);
    for (int idx = threadIdx.x; idx < 2112; idx += 256) {
        int pos = idx >> 4, c = idx & 15;
        int p2;
        if (pos < 34) p2 = pos;
        else if (pos < 68) p2 = 33 * 34 + (pos - 34);
        else if (pos < 100) p2 = (pos - 68 + 1) * 34;
        else p2 = (pos - 100 + 1) * 34 + 33;
        base[p2 * 16 + c] = z;
    }
}

// ---------------- K4d: prep LeFF fp16 weight tables (runs AFTER k_inv) --------
__global__ __launch_bounds__(256) void k_prep_leff(const float* __restrict__ DW,
                                                   const float* __restrict__ DB,
                                                   const float* __restrict__ W2,
                                                   const float* __restrict__ W1,
                                                   __half2* __restrict__ DWh,
                                                   __half2* __restrict__ DBh,
                                                   __half* __restrict__ W2T,
                                                   __half* __restrict__ W1T) {
    int gid = blockIdx.x * 256 + threadIdx.x;
    int stride = gridDim.x * 256;
    for (int i = gid; i < 1152; i += stride) {
        int tap = i >> 7, pr = i & 127;
        DWh[i] = __floats2half2_rn(DW[(2 * pr) * 9 + tap], DW[(2 * pr + 1) * 9 + tap]);
    }
    for (int i = gid; i < 128; i += stride)
        DBh[i] = __floats2half2_rn(DB[2 * i], DB[2 * i + 1]);
    for (int i = gid; i < 16384; i += stride) {
        int n = i >> 8, k = i & 255;
        W2T[i] = __float2half(W2[k * 64 + n]);
    }
    for (int i = gid; i < 16384; i += stride)
        W1T[i] = __float2half(W1[(i & 63) * 256 + (i >> 6)]);
}

// ---------------- K5: LN2 + lin1(MFMA fp16) + GELU -> H1 fp16 padded ----------
__global__ __launch_bounds__(256) void k_leff1m(const float* __restrict__ X1,
                                                const float* __restrict__ g2,
                                                const float* __restrict__ be2,
                                                const __half* __restrict__ W1T,
                                                const float* __restrict__ B1,
                                                __half* __restrict__ H1h) {
    __shared__ __half xnh[64][72];
    int tid = threadIdx.x;
    int wid = tid >> 6, lane = tid & 63;
    int lr = lane & 15, kg = lane >> 4;
    int bimg = blockIdx.x >> 4;
    int hw0 = (blockIdx.x & 15) << 6;
    size_t tok0 = (size_t)blockIdx.x * 64;
    int ltok = wid * 16 + lr;
    {
        const float4* xp = (const float4*)(X1 + (tok0 + ltok) * 64 + kg * 16);
        float4 v0 = xp[0], v1 = xp[1], v2 = xp[2], v3 = xp[3];
        float s = v0.x + v0.y + v0.z + v0.w + v1.x + v1.y + v1.z + v1.w +
                  v2.x + v2.y + v2.z + v2.w + v3.x + v3.y + v3.z + v3.w;
        float ss = v0.x * v0.x + v0.y * v0.y + v0.z * v0.z + v0.w * v0.w +
                   v1.x * v1.x + v1.y * v1.y + v1.z * v1.z + v1.w * v1.w +
                   v2.x * v2.x + v2.y * v2.y + v2.z * v2.z + v2.w * v2.w +
                   v3.x * v3.x + v3.y * v3.y + v3.z * v3.z + v3.w * v3.w;
        s += __shfl_xor(s, 16, 64);
        ss += __shfl_xor(ss, 16, 64);
        s += __shfl_xor(s, 32, 64);
        ss += __shfl_xor(ss, 32, 64);
        float m = s * (1.f / 64.f);
        float var = ss * (1.f / 64.f) - m * m;
        float rstd = rsqrtf(var + 1e-5f);
        float vv[16] = {v0.x, v0.y, v0.z, v0.w, v1.x, v1.y, v1.z, v1.w,
                        v2.x, v2.y, v2.z, v2.w, v3.x, v3.y, v3.z, v3.w};
        unsigned int u[8];
#pragma unroll
        for (int i = 0; i < 8; ++i) {
            int d = kg * 16 + 2 * i;
            float a0 = (vv[2 * i] - m) * rstd * g2[d] + be2[d];
            float a1 = (vv[2 * i + 1] - m) * rstd * g2[d + 1] + be2[d + 1];
            __half2 hh = __floats2half2_rn(a0, a1);
            u[i] = *(unsigned int*)&hh;
        }
        *(uint4*)&xnh[ltok][kg * 16] = make_uint4(u[0], u[1], u[2], u[3]);
        *(uint4*)&xnh[ltok][kg * 16 + 8] = make_uint4(u[4], u[5], u[6], u[7]);
    }
    __syncthreads();
    f32x4 acc[16];
#pragma unroll
    for (int n = 0; n < 16; ++n) acc[n] = (f32x4){0.f, 0.f, 0.f, 0.f};
#pragma unroll
    for (int k0 = 0; k0 < 2; ++k0) {
        f16x8 a = *(const f16x8*)&xnh[wid * 16 + lr][k0 * 32 + kg * 8];
#pragma unroll
        for (int n = 0; n < 16; ++n) {
            f16x8 bf = *(const f16x8*)(W1T + (size_t)(n * 16 + lr) * 64 + k0 * 32 + kg * 8);
            acc[n] = __builtin_amdgcn_mfma_f32_16x16x32_f16(a, bf, acc[n], 0, 0, 0);
        }
    }
#pragma unroll
    for (int n = 0; n < 16; ++n) {
        int hid = n * 16 + lr;
        float bb = B1[hid];
        size_t cb = ((size_t)bimg * 8 + (hid >> 5)) * 1156;
        int cl = hid & 31;
#pragma unroll
        for (int reg = 0; reg < 4; ++reg) {
            int token = wid * 16 + kg * 4 + reg;
            int hw = hw0 + token;
            int h = hw >> 5, w = hw & 31;
            H1h[(cb + (size_t)(h + 1) * 34 + (w + 1)) * 32 + cl] =
                __float2half(gelu_fast(acc[n][reg] + bb));
        }
    }
}

// ---------------- K6: fused dwconv+GELU+lin2(MFMA), 2 rows/wave ---------------
struct Tap12 { uint4 v[12]; };

__device__ __forceinline__ void load12(const __half* H1h, size_t pb, int kg, Tap12& T) {
    const __half2* p = (const __half2*)(H1h + pb * 32) + kg * 4;
#pragma unroll
    for (int r = 0; r < 4; ++r)
#pragma unroll
        for (int dc = 0; dc < 3; ++dc)
            T.v[r * 3 + dc] = *(const uint4*)(p + ((r - 1) * 34 + (dc - 1)) * 16);
}

__device__ __forceinline__ void convg2(const Tap12& T,
                                       const __half2* __restrict__ DBh,
                                       const __half2* __restrict__ DWh,
                                       int k0, int kg, f16x8& a0out, f16x8& a1out) {
    const __half2* dbp = DBh + k0 * 16 + kg * 4;
    __half2 c00 = dbp[0], c01 = dbp[1], c02 = dbp[2], c03 = dbp[3];
    __half2 c10 = c00, c11 = c01, c12 = c02, c13 = c03;
#pragma unroll
    for (int dr = 0; dr < 3; ++dr) {
#pragma unroll
        for (int dc = 0; dc < 3; ++dc) {
            const __half2* wp = DWh + (dr * 3 + dc) * 128 + k0 * 16 + kg * 4;
            __half2 w0 = wp[0], w1 = wp[1], w2 = wp[2], w3 = wp[3];
            const uint4& t0 = T.v[dr * 3 + dc];
            const uint4& t1 = T.v[(dr + 1) * 3 + dc];
            c00 = __hfma2(u2h2(t0.x), w0, c00);
            c01 = __hfma2(u2h2(t0.y), w1, c01);
            c02 = __hfma2(u2h2(t0.z), w2, c02);
            c03 = __hfma2(u2h2(t0.w), w3, c03);
            c10 = __hfma2(u2h2(t1.x), w0, c10);
            c11 = __hfma2(u2h2(t1.y), w1, c11);
            c12 = __hfma2(u2h2(t1.z), w2, c12);
            c13 = __hfma2(u2h2(t1.w), w3, c13);
        }
    }
    __half2 o0 = __floats2half2_rn(gelu_fast(__low2float(c00)), gelu_fast(__high2float(c00)));
    __half2 o1 = __floats2half2_rn(gelu_fast(__low2float(c01)), gelu_fast(__high2float(c01)));
    __half2 o2 = __floats2half2_rn(gelu_fast(__low2float(c02)), gelu_fast(__high2float(c02)));
    __half2 o3 = __floats2half2_rn(gelu_fast(__low2float(c03)), gelu_fast(__high2float(c03)));
    uint4 av0 = make_uint4(*(unsigned int*)&o0, *(unsigned int*)&o1,
                           *(unsigned int*)&o2, *(unsigned int*)&o3);
    a0out = *(f16x8*)&av0;
    o0 = __floats2half2_rn(gelu_fast(__low2float(c10)), gelu_fast(__high2float(c10)));
    o1 = __floats2half2_rn(gelu_fast(__low2float(c11)), gelu_fast(__high2float(c11)));
    o2 = __floats2half2_rn(gelu_fast(__low2float(c12)), gelu_fast(__high2float(c12)));
    o3 = __floats2half2_rn(gelu_fast(__low2float(c13)), gelu_fast(__high2float(c13)));
    uint4 av1 = make_uint4(*(unsigned int*)&o0, *(unsigned int*)&o1,
                           *(unsigned int*)&o2, *(unsigned int*)&o3);
    a1out = *(f16x8*)&av1;
}

__global__ __launch_bounds__(256, 3) void k_leff2m(const __half* __restrict__ H1h,
                                                   const __half2* __restrict__ DWh,
                                                   const __half2* __restrict__ DBh,
                                                   const __half* __restrict__ W2T,
                                                   const float* __restrict__ B2,
                                                   float* __restrict__ out) {
    int tid = threadIdx.x;
    int wid = tid >> 6, lane = tid & 63;
    int mt = blockIdx.x * 4 + wid;   // 0..8191
    int b = mt >> 5;
    int rem = mt & 31;
    int h0 = (rem >> 1) * 2;
    int w0 = (rem & 1) << 4;
    int lr = lane & 15, kg = lane >> 4;
    int wA = w0 + lr;

    f32x4 acc0[4], acc1[4];
#pragma unroll
    for (int n = 0; n < 4; ++n) {
        acc0[n] = (f32x4){0.f, 0.f, 0.f, 0.f};
        acc1[n] = (f32x4){0.f, 0.f, 0.f, 0.f};
    }

    size_t rowoff = (size_t)h0 * 34 + wA;
    Tap12 TA, TB;
    load12(H1h, ((size_t)b * 8 + 0) * 1156 + rowoff + 35, kg, TA);
#pragma unroll
    for (int k0 = 0; k0 < 8; ++k0) {
        if (k0 < 7)
            load12(H1h, ((size_t)b * 8 + (k0 + 1)) * 1156 + rowoff + 35, kg,
                   (k0 & 1) ? TA : TB);
        f16x8 a0, a1;
        convg2((k0 & 1) ? TB : TA, DBh, DWh, k0, kg, a0, a1);
#pragma unroll
        for (int n = 0; n < 4; ++n) {
            f16x8 bf = *(const f16x8*)(W2T + ((size_t)(n * 16 + lr) * 256 + k0 * 32 + kg * 8));
            acc0[n] = __builtin_amdgcn_mfma_f32_16x16x32_f16(a0, bf, acc0[n], 0, 0, 0);
            acc1[n] = __builtin_amdgcn_mfma_f32_16x16x32_f16(a1, bf, acc1[n], 0, 0, 0);
        }
    }
    size_t ob0 = (size_t)b * 1024 + (size_t)h0 * 32;
#pragma unroll
    for (int n = 0; n < 4; ++n) {
        int c = n * 16 + lr;
        float b2v = B2[c];
#pragma unroll
        for (int reg = 0; reg < 4; ++reg) {
            int rowTok = w0 + kg * 4 + reg;
            size_t g0i = (ob0 + rowTok) * 64 + c;
            out[g0i] += acc0[n][reg] + b2v;
            size_t g1i = (ob0 + 32 + rowTok) * 64 + c;
            out[g1i] += acc1[n][reg] + b2v;
        }
    }
}

extern "C" void kernel_launch(void* const* d_in, const int* in_sizes, int n_in,
                              void* d_out, int out_size, void* d_ws, size_t ws_size,
                              hipStream_t stream) {
    const float* x = (const float*)d_in[0];
    const float* ln1_g = (const float*)d_in[1];
    const float* ln1_b = (const float*)d_in[2];
    const float* w_ll = (const float*)d_in[3];
    const float* w1 = (const float*)d_in[4];
    const float* w2 = (const float*)d_in[5];
    const float* b1 = (const float*)d_in[6];
    const float* b2 = (const float*)d_in[7];
    const float* ln2_g = (const float*)d_in[8];
    const float* ln2_b = (const float*)d_in[9];
    const float* lin1_w = (const float*)d_in[10];
    const float* lin1_b = (const float*)d_in[11];
    const float* dw_w = (const float*)d_in[12];
    const float* dw_b = (const float*)d_in[13];
    const float* lin2_w = (const float*)d_in[14];
    const float* lin2_b = (const float*)d_in[15];
    float* out = (float*)d_out;
    char* ws = (char*)d_ws;

    // Lifetimes (R17 layout, measured-best):
    //  Ah   [0, 33.5MB)     : LN1 out; dead after k_fwd. Reused: mlp tables, Yh, H1h.
    //  HSr  [64MiB, 112MiB) : live k_fwd..k_inv.
    //  HSi  [160MiB, 208MiB): live k_fwd..k_inv. Reused after inv: leff tables.
    //  Yh   [0, 33.5MB)     : k_inv writes, k_addt reads; dead before k_halo.
    //  H1h  [0, 144.5MiB)   : k_halo/k_leff1m write, k_leff2m reads.
    __half* Ah = (__half*)ws;
    __half* HSr = (__half*)(ws + 67108864);
    __half* HSi = (__half*)(ws + 167772160);
    float* LL = out;
    __half* Yh = (__half*)ws;
    __half* H1h = (__half*)ws;
    __half* W1cr = (__half*)(ws);
    __half* W1ci = (__half*)(ws + 4096);
    __half* W2cr = (__half*)(ws + 8192);
    __half* W2ci = (__half*)(ws + 12288);
    char* wtab = ws + 167772160;
    __half2* DWh = (__half2*)(wtab);
    __half2* DBh = (__half2*)(wtab + 8192);
    __half* W2T = (__half*)(wtab + 12288);
    __half* W1T = (__half*)(wtab + 49152);

    k_ln1_t<<<dim3(4096), dim3(256), 0, stream>>>(x, ln1_g, ln1_b, Ah);
    k_fwd<<<dim3(16384), dim3(256), 0, stream>>>(Ah, w_ll, LL, HSr, HSi);
    k_prep_mlp<<<dim3(8), dim3(256), 0, stream>>>(w1, w2, W1cr, W1ci, W2cr, W2ci);
    k_mlpm<<<dim3(1536), dim3(256), 0, stream>>>(HSr, HSi, W1cr, W1ci, W2cr, W2ci, b1, b2);
    k_inv<<<dim3(16384), dim3(256), 0, stream>>>(LL, HSr, HSi, Yh);
    k_addt<<<dim3(4096), dim3(256), 0, stream>>>(Yh, x, out);
    k_halo<<<dim3(2048), dim3(256), 0, stream>>>((__half2*)H1h);
    k_prep_leff<<<dim3(72), dim3(256), 0, stream>>>(dw_w, dw_b, lin2_w, lin1_w,
                                                    DWh, DBh, W2T, W1T);
    k_leff1m<<<dim3(4096), dim3(256), 0, stream>>>(out, ln2_g, ln2_b, W1T, lin1_b, H1h);
    k_leff2m<<<dim3(2048), dim3(256), 0, stream>>>(H1h, DWh, DBh, W2T, b2, out);
}

// Round 21
// 454.499 us; speedup vs baseline: 1.0837x; 1.0384x over previous
//
#include <hip/hip_runtime.h>
#include <hip/hip_fp16.h>
#include <math.h>

#define ISQ2 0.70710678118654752440f

typedef _Float16 f16x8 __attribute__((ext_vector_type(8)));
typedef __attribute__((ext_vector_type(4))) float f32x4;

static __device__ __constant__ float H0c[13] = {
    -0.0017578f, 0.0f, 0.0222656f, -0.046875f, -0.0482422f, 0.296875f,
    0.5554688f, 0.296875f, -0.0482422f, -0.046875f, 0.0222656f, 0.0f, -0.0017578f};
static __device__ __constant__ float H1c[19] = {
    -7.06e-05f, 0.0f, 0.0013419f, -0.0018834f, -0.0071568f, 0.023856f,
    0.0556431f, -0.0516881f, -0.2997576f, 0.5594308f, -0.2997576f, -0.0516881f,
    0.0556431f, 0.023856f, -0.0071568f, -0.0018834f, 0.0013419f, 0.0f, -7.06e-05f};

__device__ __forceinline__ int refl32(int i) {
    if (i < 0) i = -1 - i;
    if (i > 31) i = 63 - i;
    return i;
}

// tanh-form GELU with hardware-rcp (v_rcp_f32, ~1ulp): |err| < ~1e-3 vs exact
__device__ __forceinline__ float gelu_fast(float x) {
    float u = x * (0.7978845608f + 0.0356774081f * x * x);
    float e = __expf(-2.0f * fabsf(u));
    float t = 1.0f - 2.0f * e * __builtin_amdgcn_rcpf(1.0f + e);
    t = copysignf(t, u);
    return 0.5f * x * (1.0f + t);
}

__device__ __forceinline__ __half2 u2h2(unsigned int u) {
    union { unsigned int u; __half2 h; } c;
    c.u = u;
    return c.h;
}

// ---------------- K1: LN1 + transpose (B,N,C)->(B,C,32,32) fp16 --------------
__global__ __launch_bounds__(256) void k_ln1_t(const float* __restrict__ x,
                                               const float* __restrict__ g,
                                               const float* __restrict__ be,
                                               __half* __restrict__ Ah) {
    __shared__ float sx[64][65];
    __shared__ float rs[64][4], rq[64][4];
    __shared__ float sm[64], sv[64];
    int b = blockIdx.x >> 4;
    int n0 = (blockIdx.x & 15) << 6;
    int tid = threadIdx.x;
    const float* xp = x + ((size_t)b * 1024 + n0) * 64;
#pragma unroll
    for (int rep = 0; rep < 16; ++rep) {
        int idx = rep * 256 + tid;
        sx[idx >> 6][idx & 63] = xp[idx];
    }
    __syncthreads();
    {
        int i = tid >> 2, q = tid & 3;
        float s = 0.f, ss = 0.f;
#pragma unroll
        for (int d = 0; d < 16; ++d) {
            float v = sx[i][q * 16 + d];
            s += v; ss += v * v;
        }
        rs[i][q] = s; rq[i][q] = ss;
    }
    __syncthreads();
    if (tid < 64) {
        float s = rs[tid][0] + rs[tid][1] + rs[tid][2] + rs[tid][3];
        float ss = rq[tid][0] + rq[tid][1] + rq[tid][2] + rq[tid][3];
        float m = s * (1.f / 64.f);
        float v = ss * (1.f / 64.f) - m * m;
        sm[tid] = m;
        sv[tid] = rsqrtf(v + 1e-5f);
    }
    __syncthreads();
#pragma unroll
    for (int rep = 0; rep < 16; ++rep) {
        int idx = rep * 256 + tid;
        int c = idx >> 6, i = idx & 63;
        float val = (sx[i][c] - sm[i]) * sv[i] * g[c] + be[c];
        Ah[((size_t)(b * 64 + c)) * 1024 + n0 + i] = __float2half(val);
    }
}

// ---------------- K2: forward DTCWT (fp16 in/out), sliding windows ------------
__global__ __launch_bounds__(256, 4) void k_fwd(const __half* __restrict__ Ah,
                                                const float* __restrict__ wll,
                                                float* __restrict__ LL,
                                                __half* __restrict__ HSr,
                                                __half* __restrict__ HSi) {
    __shared__ float sx[32][52];
    __shared__ float slo[50][34];
    __shared__ float shi[50][34];
    int bc = blockIdx.x;
    int c = bc & 63;
    int tid = threadIdx.x;
    int hA = tid >> 3, w0r = (tid & 7) * 4;
    {
        const __half2* ap2 = (const __half2*)(Ah + (size_t)bc * 1024);
        __half2 v01 = ap2[tid * 2], v23 = ap2[tid * 2 + 1];
        sx[hA][w0r + 9] = __low2float(v01);
        sx[hA][w0r + 10] = __high2float(v01);
        sx[hA][w0r + 11] = __low2float(v23);
        sx[hA][w0r + 12] = __high2float(v23);
    }
    __syncthreads();
    for (int i = tid; i < 576; i += 256) {
        int h = i / 18, j = i - (i / 18) * 18;
        int wp = (j < 9) ? (j - 9) : (23 + j);
        sx[h][wp + 9] = sx[h][refl32(wp) + 9];
    }
    __syncthreads();
    {
        float ws[22];
#pragma unroll
        for (int t = 0; t < 22; ++t) ws[t] = sx[hA][w0r + t];
        float lo[4] = {0.f, 0.f, 0.f, 0.f}, hi[4] = {0.f, 0.f, 0.f, 0.f};
#pragma unroll
        for (int k = 0; k < 19; ++k)
#pragma unroll
            for (int j = 0; j < 4; ++j) hi[j] += H1c[k] * ws[j + k];
#pragma unroll
        for (int k = 0; k < 13; ++k)
#pragma unroll
            for (int j = 0; j < 4; ++j) lo[j] += H0c[k] * ws[j + k + 3];
#pragma unroll
        for (int j = 0; j < 4; ++j) {
            slo[hA + 9][w0r + j] = lo[j];
            shi[hA + 9][w0r + j] = hi[j];
        }
    }
    __syncthreads();
    for (int i = tid; i < 576; i += 256) {
        int j = i >> 5, w = i & 31;
        int hp = (j < 9) ? (j - 9) : (23 + j);
        int hs = refl32(hp);
        slo[hp + 9][w] = slo[hs + 9][w];
        shi[hp + 9][w] = shi[hs + 9][w];
    }
    __syncthreads();
    {
        int wL = tid & 31, h0 = (tid >> 5) * 4;
        float cs[16];
#pragma unroll
        for (int t = 0; t < 16; ++t) cs[t] = slo[h0 + 3 + t][wL];
#pragma unroll
        for (int j = 0; j < 4; ++j) {
            float acc = 0.f;
#pragma unroll
            for (int k = 0; k < 13; ++k) acc += H0c[k] * cs[j + k];
            int p = (h0 + j) * 32 + wL;
            LL[(size_t)bc * 1024 + p] = acc * wll[c * 1024 + p];
        }
    }
    {
        int i = tid >> 4, j = tid & 15;
        size_t base = (size_t)bc * 1536 + tid;
        float a, bb, cc2, dd;
        {
            float2 sl[20];
#pragma unroll
            for (int t = 0; t < 20; ++t) sl[t] = *(const float2*)&slo[2 * i + t][2 * j];
            a = bb = cc2 = dd = 0.f;
#pragma unroll
            for (int k = 0; k < 19; ++k) {
                a += H1c[k] * sl[k].x;
                bb += H1c[k] * sl[k].y;
                cc2 += H1c[k] * sl[k + 1].x;
                dd += H1c[k] * sl[k + 1].y;
            }
            HSr[base + 0 * 256] = __float2half((a - dd) * ISQ2);
            HSi[base + 0 * 256] = __float2half((bb + cc2) * ISQ2);
            HSr[base + 5 * 256] = __float2half((a + dd) * ISQ2);
            HSi[base + 5 * 256] = __float2half((bb - cc2) * ISQ2);
        }
        {
            float2 sh[20];
#pragma unroll
            for (int t = 0; t < 20; ++t) sh[t] = *(const float2*)&shi[2 * i + t][2 * j];
            a = bb = cc2 = dd = 0.f;
#pragma unroll
            for (int k = 0; k < 19; ++k) {
                a += H1c[k] * sh[k].x;
                bb += H1c[k] * sh[k].y;
                cc2 += H1c[k] * sh[k + 1].x;
                dd += H1c[k] * sh[k + 1].y;
            }
            HSr[base + 1 * 256] = __float2half((a - dd) * ISQ2);
            HSi[base + 1 * 256] = __float2half((bb + cc2) * ISQ2);
            HSr[base + 4 * 256] = __float2half((a + dd) * ISQ2);
            HSi[base + 4 * 256] = __float2half((bb - cc2) * ISQ2);
            a = bb = cc2 = dd = 0.f;
#pragma unroll
            for (int k = 0; k < 13; ++k) {
                a += H0c[k] * sh[k + 3].x;
                bb += H0c[k] * sh[k + 3].y;
                cc2 += H0c[k] * sh[k + 4].x;
                dd += H0c[k] * sh[k + 4].y;
            }
            HSr[base + 2 * 256] = __float2half((a - dd) * ISQ2);
            HSi[base + 2 * 256] = __float2half((bb + cc2) * ISQ2);
            HSr[base + 3 * 256] = __float2half((a + dd) * ISQ2);
            HSi[base + 3 * 256] = __float2half((bb - cc2) * ISQ2);
        }
    }
}

// ---------------- K2b: prep complex-MLP fp16 B-frags (runs AFTER k_fwd) -------
__global__ __launch_bounds__(256) void k_prep_mlp(const float* __restrict__ mw1,
                                                  const float* __restrict__ mw2,
                                                  __half* __restrict__ W1cr,
                                                  __half* __restrict__ W1ci,
                                                  __half* __restrict__ W2cr,
                                                  __half* __restrict__ W2ci) {
    int gid = blockIdx.x * 256 + threadIdx.x;
    int stride = gridDim.x * 256;
    for (int i = gid; i < 2048; i += stride) {
        int q = i >> 9, rest = i & 511;
        int n = rest >> 5, k = rest & 31;
        if (k < 16) {
            W1cr[i] = __float2half(mw1[q * 256 + k * 16 + n]);
            W1ci[i] = __float2half(mw1[1024 + q * 256 + k * 16 + n]);
            W2cr[i] = __float2half(mw2[q * 256 + k * 16 + n]);
            W2ci[i] = __float2half(mw2[1024 + q * 256 + k * 16 + n]);
        } else {
            W1cr[i] = __float2half(-mw1[1024 + q * 256 + (k - 16) * 16 + n]);
            W1ci[i] = __float2half(mw1[q * 256 + (k - 16) * 16 + n]);
            W2cr[i] = __float2half(-mw2[1024 + q * 256 + (k - 16) * 16 + n]);
            W2ci[i] = __float2half(mw2[q * 256 + (k - 16) * 16 + n]);
        }
    }
}

// ---------------- K3: complex block-MLP via MFMA, fp16 HS in/out --------------
__global__ __launch_bounds__(256) void k_mlpm(__half* __restrict__ HSr,
                                              __half* __restrict__ HSi,
                                              const __half* __restrict__ W1cr,
                                              const __half* __restrict__ W1ci,
                                              const __half* __restrict__ W2cr,
                                              const __half* __restrict__ W2ci,
                                              const float* __restrict__ b1,
                                              const float* __restrict__ b2) {
    __shared__ __half xh[4][64][40];
    int tid = threadIdx.x;
    int wid = tid >> 6, lane = tid & 63;
    int lr = lane & 15, kg = lane >> 4;
    int b = blockIdx.x / 6;
    int o = blockIdx.x - b * 6;
    size_t base = (size_t)b * 98304 + (size_t)o * 256;

#pragma unroll 1
    for (int q = 0; q < 4; ++q) {
#pragma unroll
        for (int mt = 0; mt < 4; ++mt) {
            int token0 = wid * 64 + mt * 16;
            const unsigned short* src =
                (const unsigned short*)((kg < 2) ? HSr : HSi);
            int c0 = q * 16 + (kg & 1) * 8;
            unsigned int u[4];
#pragma unroll
            for (int e = 0; e < 4; ++e) {
                unsigned int lo = src[base + (size_t)(c0 + 2 * e) * 1536 + token0 + lr];
                unsigned int hi = src[base + (size_t)(c0 + 2 * e + 1) * 1536 + token0 + lr];
                u[e] = lo | (hi << 16);
            }
            uint4 av = make_uint4(u[0], u[1], u[2], u[3]);
            f16x8 a = *(f16x8*)&av;
            f16x8 bfr = *(const f16x8*)(W1cr + q * 512 + lr * 32 + kg * 8);
            f16x8 bfi = *(const f16x8*)(W1ci + q * 512 + lr * 32 + kg * 8);
            f32x4 accr = (f32x4){0.f, 0.f, 0.f, 0.f};
            f32x4 acci = (f32x4){0.f, 0.f, 0.f, 0.f};
            accr = __builtin_amdgcn_mfma_f32_16x16x32_f16(a, bfr, accr, 0, 0, 0);
            acci = __builtin_amdgcn_mfma_f32_16x16x32_f16(a, bfi, acci, 0, 0, 0);
            float b1r = b1[q * 16 + lr];
            float b1i = b1[64 + q * 16 + lr];
#pragma unroll
            for (int reg = 0; reg < 4; ++reg) {
                int tl = mt * 16 + kg * 4 + reg;
                xh[wid][tl][lr] = __float2half(fmaxf(accr[reg] + b1r, 0.f));
                xh[wid][tl][16 + lr] = __float2half(fmaxf(acci[reg] + b1i, 0.f));
            }
        }
        __syncthreads();
#pragma unroll
        for (int mt = 0; mt < 4; ++mt) {
            f16x8 a = *(const f16x8*)&xh[wid][mt * 16 + lr][kg * 8];
            f16x8 bfr = *(const f16x8*)(W2cr + q * 512 + lr * 32 + kg * 8);
            f16x8 bfi = *(const f16x8*)(W2ci + q * 512 + lr * 32 + kg * 8);
            f32x4 accr = (f32x4){0.f, 0.f, 0.f, 0.f};
            f32x4 acci = (f32x4){0.f, 0.f, 0.f, 0.f};
            accr = __builtin_amdgcn_mfma_f32_16x16x32_f16(a, bfr, accr, 0, 0, 0);
            acci = __builtin_amdgcn_mfma_f32_16x16x32_f16(a, bfi, acci, 0, 0, 0);
            float b2r = b2[q * 16 + lr];
            float b2i = b2[64 + q * 16 + lr];
            size_t cb = base + (size_t)(q * 16 + lr) * 1536 + wid * 64 + mt * 16 + kg * 4;
#pragma unroll
            for (int reg = 0; reg < 4; ++reg) {
                HSr[cb + reg] = __float2half(accr[reg] + b2r);
                HSi[cb + reg] = __float2half(acci[reg] + b2i);
            }
        }
        __syncthreads();
    }
}

// ---------------- K4: inverse DTCWT (fp16 in/out), sliding windows ------------
__global__ __launch_bounds__(256, 4) void k_inv(const float* __restrict__ LL,
                                                const __half* __restrict__ HSr,
                                                const __half* __restrict__ HSi,
                                                __half* __restrict__ Yh) {
    __shared__ float sll[50][34], slh[50][34], shl[50][34], shh[50][34];
    __shared__ float slo[32][52], shi[32][52];
    int bc = blockIdx.x;
    int tid = threadIdx.x;
    int hA = tid >> 3, w0r = (tid & 7) * 4;
    {
        const float4* lp4 = (const float4*)(LL + (size_t)bc * 1024);
        float4 v = lp4[tid];
        sll[hA + 9][w0r] = v.x;
        sll[hA + 9][w0r + 1] = v.y;
        sll[hA + 9][w0r + 2] = v.z;
        sll[hA + 9][w0r + 3] = v.w;
    }
    {
        int i = tid >> 4, j = tid & 15;
        int h0 = 2 * i + 9, w0 = 2 * j;
        size_t base = (size_t)bc * 1536 + tid;
        float o0r = __half2float(HSr[base + 0 * 256]), o0i = __half2float(HSi[base + 0 * 256]);
        float o1r = __half2float(HSr[base + 1 * 256]), o1i = __half2float(HSi[base + 1 * 256]);
        float o2r = __half2float(HSr[base + 2 * 256]), o2i = __half2float(HSi[base + 2 * 256]);
        float o3r = __half2float(HSr[base + 3 * 256]), o3i = __half2float(HSi[base + 3 * 256]);
        float o4r = __half2float(HSr[base + 4 * 256]), o4i = __half2float(HSi[base + 4 * 256]);
        float o5r = __half2float(HSr[base + 5 * 256]), o5i = __half2float(HSi[base + 5 * 256]);
        *(float2*)&slh[h0][w0] = make_float2((o0r + o5r) * ISQ2, (o0i + o5i) * ISQ2);
        *(float2*)&slh[h0 + 1][w0] = make_float2((o0i - o5i) * ISQ2, (o5r - o0r) * ISQ2);
        *(float2*)&shl[h0][w0] = make_float2((o2r + o3r) * ISQ2, (o2i + o3i) * ISQ2);
        *(float2*)&shl[h0 + 1][w0] = make_float2((o2i - o3i) * ISQ2, (o3r - o2r) * ISQ2);
        *(float2*)&shh[h0][w0] = make_float2((o1r + o4r) * ISQ2, (o1i + o4i) * ISQ2);
        *(float2*)&shh[h0 + 1][w0] = make_float2((o1i - o4i) * ISQ2, (o4r - o1r) * ISQ2);
    }
    __syncthreads();
    for (int i = tid; i < 576; i += 256) {
        int j = i >> 5, w = i & 31;
        int hp = (j < 9) ? (j - 9) : (23 + j);
        int hs = refl32(hp);
        sll[hp + 9][w] = sll[hs + 9][w];
        slh[hp + 9][w] = slh[hs + 9][w];
        shl[hp + 9][w] = shl[hs + 9][w];
        shh[hp + 9][w] = shh[hs + 9][w];
    }
    __syncthreads();
    {
        int wL = tid & 31, h0 = (tid >> 5) * 4;
        float w19[22], w13[16];
        float lo[4] = {0.f, 0.f, 0.f, 0.f}, hi[4] = {0.f, 0.f, 0.f, 0.f};
#pragma unroll
        for (int t = 0; t < 22; ++t) w19[t] = sll[h0 + t][wL];
#pragma unroll
        for (int k = 0; k < 19; ++k) {
            float g0 = (k & 1) ? H1c[k] : -H1c[k];
#pragma unroll
            for (int j = 0; j < 4; ++j) lo[j] += g0 * w19[j + k];
        }
#pragma unroll
        for (int t = 0; t < 16; ++t) w13[t] = slh[h0 + 3 + t][wL];
#pragma unroll
        for (int k = 0; k < 13; ++k) {
            float g1 = (k & 1) ? H0c[k] : -H0c[k];
#pragma unroll
            for (int j = 0; j < 4; ++j) lo[j] += g1 * w13[j + k];
        }
#pragma unroll
        for (int t = 0; t < 22; ++t) w19[t] = shl[h0 + t][wL];
#pragma unroll
        for (int k = 0; k < 19; ++k) {
            float g0 = (k & 1) ? H1c[k] : -H1c[k];
#pragma unroll
            for (int j = 0; j < 4; ++j) hi[j] += g0 * w19[j + k];
        }
#pragma unroll
        for (int t = 0; t < 16; ++t) w13[t] = shh[h0 + 3 + t][wL];
#pragma unroll
        for (int k = 0; k < 13; ++k) {
            float g1 = (k & 1) ? H0c[k] : -H0c[k];
#pragma unroll
            for (int j = 0; j < 4; ++j) hi[j] += g1 * w13[j + k];
        }
#pragma unroll
        for (int j = 0; j < 4; ++j) {
            slo[h0 + j][wL + 9] = lo[j];
            shi[h0 + j][wL + 9] = hi[j];
        }
    }
    __syncthreads();
    for (int i = tid; i < 576; i += 256) {
        int h = i / 18, j = i - (i / 18) * 18;
        int wp = (j < 9) ? (j - 9) : (23 + j);
        int ws2 = refl32(wp);
        slo[h][wp + 9] = slo[h][ws2 + 9];
        shi[h][wp + 9] = shi[h][ws2 + 9];
    }
    __syncthreads();
    {
        float rw[22], rh[16];
#pragma unroll
        for (int t = 0; t < 22; ++t) rw[t] = slo[hA][w0r + t];
#pragma unroll
        for (int t = 0; t < 16; ++t) rh[t] = shi[hA][w0r + 3 + t];
        float y[4] = {0.f, 0.f, 0.f, 0.f};
#pragma unroll
        for (int k = 0; k < 19; ++k) {
            float g0 = (k & 1) ? H1c[k] : -H1c[k];
#pragma unroll
            for (int j = 0; j < 4; ++j) y[j] += g0 * rw[j + k];
        }
#pragma unroll
        for (int k = 0; k < 13; ++k) {
            float g1 = (k & 1) ? H0c[k] : -H0c[k];
#pragma unroll
            for (int j = 0; j < 4; ++j) y[j] += g1 * rh[j + k];
        }
        __half2 y01 = __floats2half2_rn(y[0], y[1]);
        __half2 y23 = __floats2half2_rn(y[2], y[3]);
        uint2 pk;
        pk.x = *(unsigned int*)&y01;
        pk.y = *(unsigned int*)&y23;
        *(uint2*)(Yh + (size_t)bc * 1024 + hA * 32 + w0r) = pk;
    }
}

// ---------------- K4b: X1 = x + Y^T -> d_out (B,N,C) ----------------
__global__ __launch_bounds__(256) void k_addt(const __half* __restrict__ Yh,
                                              const float* __restrict__ x,
                                              float* __restrict__ out) {
    __shared__ float sy[64][65];
    int b = blockIdx.x >> 4;
    int n0 = (blockIdx.x & 15) << 6;
    int tid = threadIdx.x;
#pragma unroll
    for (int rep = 0; rep < 16; ++rep) {
        int idx = rep * 256 + tid;
        int c = idx >> 6, i = idx & 63;
        sy[c][i] = __half2float(Yh[((size_t)(b * 64 + c)) * 1024 + n0 + i]);
    }
    __syncthreads();
#pragma unroll
    for (int rep = 0; rep < 16; ++rep) {
        int idx = rep * 256 + tid;
        int i = idx >> 6, c = idx & 63;
        size_t gi = ((size_t)b * 1024 + n0 + i) * 64 + c;
        out[gi] = x[gi] + sy[c][i];
    }
}

// ---------------- K4c: zero the halo of padded H1 (b,k0,34,34,32) fp16 --------
__global__ __launch_bounds__(256) void k_halo(__half2* __restrict__ H1h2) {
    int img = blockIdx.x;  // 2048
    __half2* base = H1h2 + (size_t)img * 1156 * 16;
    __half2 z = __floats2half2_rn(0.f, 0.f);
    for (int idx = threadIdx.x; idx < 2112; idx += 256) {
        int pos = idx >> 4, c = idx & 15;
        int p2;
        if (pos < 34) p2 = pos;
        else if (pos < 68) p2 = 33 * 34 + (pos - 34);
        else if (pos < 100) p2 = (pos - 68 + 1) * 34;
        else p2 = (pos - 100 + 1) * 34 + 33;
        base[p2 * 16 + c] = z;
    }
}

// ---------------- K4d: prep LeFF fp16 weight tables (runs AFTER k_inv) --------
__global__ __launch_bounds__(256) void k_prep_leff(const float* __restrict__ DW,
                                                   const float* __restrict__ DB,
                                                   const float* __restrict__ W2,
                                                   const float* __restrict__ W1,
                                                   __half2* __restrict__ DWh,
                                                   __half2* __restrict__ DBh,
                                                   __half* __restrict__ W2T,
                                                   __half* __restrict__ W1T) {
    int gid = blockIdx.x * 256 + threadIdx.x;
    int stride = gridDim.x * 256;
    for (int i = gid; i < 1152; i += stride) {
        int tap = i >> 7, pr = i & 127;
        DWh[i] = __floats2half2_rn(DW[(2 * pr) * 9 + tap], DW[(2 * pr + 1) * 9 + tap]);
    }
    for (int i = gid; i < 128; i += stride)
        DBh[i] = __floats2half2_rn(DB[2 * i], DB[2 * i + 1]);
    for (int i = gid; i < 16384; i += stride) {
        int n = i >> 8, k = i & 255;
        W2T[i] = __float2half(W2[k * 64 + n]);
    }
    for (int i = gid; i < 16384; i += stride)
        W1T[i] = __float2half(W1[(i & 63) * 256 + (i >> 6)]);
}

// ---------------- K5: LN2 + lin1(MFMA fp16) + GELU -> H1 fp16 padded ----------
__global__ __launch_bounds__(256) void k_leff1m(const float* __restrict__ X1,
                                                const float* __restrict__ g2,
                                                const float* __restrict__ be2,
                                                const __half* __restrict__ W1T,
                                                const float* __restrict__ B1,
                                                __half* __restrict__ H1h) {
    __shared__ __half xnh[64][72];
    int tid = threadIdx.x;
    int wid = tid >> 6, lane = tid & 63;
    int lr = lane & 15, kg = lane >> 4;
    int bimg = blockIdx.x >> 4;
    int hw0 = (blockIdx.x & 15) << 6;
    size_t tok0 = (size_t)blockIdx.x * 64;
    int ltok = wid * 16 + lr;
    {
        const float4* xp = (const float4*)(X1 + (tok0 + ltok) * 64 + kg * 16);
        float4 v0 = xp[0], v1 = xp[1], v2 = xp[2], v3 = xp[3];
        float s = v0.x + v0.y + v0.z + v0.w + v1.x + v1.y + v1.z + v1.w +
                  v2.x + v2.y + v2.z + v2.w + v3.x + v3.y + v3.z + v3.w;
        float ss = v0.x * v0.x + v0.y * v0.y + v0.z * v0.z + v0.w * v0.w +
                   v1.x * v1.x + v1.y * v1.y + v1.z * v1.z + v1.w * v1.w +
                   v2.x * v2.x + v2.y * v2.y + v2.z * v2.z + v2.w * v2.w +
                   v3.x * v3.x + v3.y * v3.y + v3.z * v3.z + v3.w * v3.w;
        s += __shfl_xor(s, 16, 64);
        ss += __shfl_xor(ss, 16, 64);
        s += __shfl_xor(s, 32, 64);
        ss += __shfl_xor(ss, 32, 64);
        float m = s * (1.f / 64.f);
        float var = ss * (1.f / 64.f) - m * m;
        float rstd = rsqrtf(var + 1e-5f);
        float vv[16] = {v0.x, v0.y, v0.z, v0.w, v1.x, v1.y, v1.z, v1.w,
                        v2.x, v2.y, v2.z, v2.w, v3.x, v3.y, v3.z, v3.w};
        unsigned int u[8];
#pragma unroll
        for (int i = 0; i < 8; ++i) {
            int d = kg * 16 + 2 * i;
            float a0 = (vv[2 * i] - m) * rstd * g2[d] + be2[d];
            float a1 = (vv[2 * i + 1] - m) * rstd * g2[d + 1] + be2[d + 1];
            __half2 hh = __floats2half2_rn(a0, a1);
            u[i] = *(unsigned int*)&hh;
        }
        *(uint4*)&xnh[ltok][kg * 16] = make_uint4(u[0], u[1], u[2], u[3]);
        *(uint4*)&xnh[ltok][kg * 16 + 8] = make_uint4(u[4], u[5], u[6], u[7]);
    }
    __syncthreads();
    f32x4 acc[16];
#pragma unroll
    for (int n = 0; n < 16; ++n) acc[n] = (f32x4){0.f, 0.f, 0.f, 0.f};
#pragma unroll
    for (int k0 = 0; k0 < 2; ++k0) {
        f16x8 a = *(const f16x8*)&xnh[wid * 16 + lr][k0 * 32 + kg * 8];
#pragma unroll
        for (int n = 0; n < 16; ++n) {
            f16x8 bf = *(const f16x8*)(W1T + (size_t)(n * 16 + lr) * 64 + k0 * 32 + kg * 8);
            acc[n] = __builtin_amdgcn_mfma_f32_16x16x32_f16(a, bf, acc[n], 0, 0, 0);
        }
    }
#pragma unroll
    for (int n = 0; n < 16; ++n) {
        int hid = n * 16 + lr;
        float bb = B1[hid];
        size_t cb = ((size_t)bimg * 8 + (hid >> 5)) * 1156;
        int cl = hid & 31;
#pragma unroll
        for (int reg = 0; reg < 4; ++reg) {
            int token = wid * 16 + kg * 4 + reg;
            int hw = hw0 + token;
            int h = hw >> 5, w = hw & 31;
            H1h[(cb + (size_t)(h + 1) * 34 + (w + 1)) * 32 + cl] =
                __float2half(gelu_fast(acc[n][reg] + bb));
        }
    }
}

// ---------------- K6: fused dwconv+GELU+lin2(MFMA), 2 rows/wave ---------------
struct Tap12 { uint4 v[12]; };

__device__ __forceinline__ void load12(const __half* H1h, size_t pb, int kg, Tap12& T) {
    const __half2* p = (const __half2*)(H1h + pb * 32) + kg * 4;
#pragma unroll
    for (int r = 0; r < 4; ++r)
#pragma unroll
        for (int dc = 0; dc < 3; ++dc)
            T.v[r * 3 + dc] = *(const uint4*)(p + ((r - 1) * 34 + (dc - 1)) * 16);
}

__device__ __forceinline__ void convg2(const Tap12& T,
                                       const __half2* __restrict__ DBh,
                                       const __half2* __restrict__ DWh,
                                       int k0, int kg, f16x8& a0out, f16x8& a1out) {
    const __half2* dbp = DBh + k0 * 16 + kg * 4;
    __half2 c00 = dbp[0], c01 = dbp[1], c02 = dbp[2], c03 = dbp[3];
    __half2 c10 = c00, c11 = c01, c12 = c02, c13 = c03;
#pragma unroll
    for (int dr = 0; dr < 3; ++dr) {
#pragma unroll
        for (int dc = 0; dc < 3; ++dc) {
            const __half2* wp = DWh + (dr * 3 + dc) * 128 + k0 * 16 + kg * 4;
            __half2 w0 = wp[0], w1 = wp[1], w2 = wp[2], w3 = wp[3];
            const uint4& t0 = T.v[dr * 3 + dc];
            const uint4& t1 = T.v[(dr + 1) * 3 + dc];
            c00 = __hfma2(u2h2(t0.x), w0, c00);
            c01 = __hfma2(u2h2(t0.y), w1, c01);
            c02 = __hfma2(u2h2(t0.z), w2, c02);
            c03 = __hfma2(u2h2(t0.w), w3, c03);
            c10 = __hfma2(u2h2(t1.x), w0, c10);
            c11 = __hfma2(u2h2(t1.y), w1, c11);
            c12 = __hfma2(u2h2(t1.z), w2, c12);
            c13 = __hfma2(u2h2(t1.w), w3, c13);
        }
    }
    __half2 o0 = __floats2half2_rn(gelu_fast(__low2float(c00)), gelu_fast(__high2float(c00)));
    __half2 o1 = __floats2half2_rn(gelu_fast(__low2float(c01)), gelu_fast(__high2float(c01)));
    __half2 o2 = __floats2half2_rn(gelu_fast(__low2float(c02)), gelu_fast(__high2float(c02)));
    __half2 o3 = __floats2half2_rn(gelu_fast(__low2float(c03)), gelu_fast(__high2float(c03)));
    uint4 av0 = make_uint4(*(unsigned int*)&o0, *(unsigned int*)&o1,
                           *(unsigned int*)&o2, *(unsigned int*)&o3);
    a0out = *(f16x8*)&av0;
    o0 = __floats2half2_rn(gelu_fast(__low2float(c10)), gelu_fast(__high2float(c10)));
    o1 = __floats2half2_rn(gelu_fast(__low2float(c11)), gelu_fast(__high2float(c11)));
    o2 = __floats2half2_rn(gelu_fast(__low2float(c12)), gelu_fast(__high2float(c12)));
    o3 = __floats2half2_rn(gelu_fast(__low2float(c13)), gelu_fast(__high2float(c13)));
    uint4 av1 = make_uint4(*(unsigned int*)&o0, *(unsigned int*)&o1,
                           *(unsigned int*)&o2, *(unsigned int*)&o3);
    a1out = *(f16x8*)&av1;
}

__global__ __launch_bounds__(256, 3) void k_leff2m(const __half* __restrict__ H1h,
                                                   const __half2* __restrict__ DWh,
                                                   const __half2* __restrict__ DBh,
                                                   const __half* __restrict__ W2T,
                                                   const float* __restrict__ B2,
                                                   float* __restrict__ out) {
    int tid = threadIdx.x;
    int wid = tid >> 6, lane = tid & 63;
    int mt = blockIdx.x * 4 + wid;   // 0..8191
    int b = mt >> 5;
    int rem = mt & 31;
    int h0 = (rem >> 1) * 2;
    int w0 = (rem & 1) << 4;
    int lr = lane & 15, kg = lane >> 4;
    int wA = w0 + lr;

    f32x4 acc0[4], acc1[4];
#pragma unroll
    for (int n = 0; n < 4; ++n) {
        acc0[n] = (f32x4){0.f, 0.f, 0.f, 0.f};
        acc1[n] = (f32x4){0.f, 0.f, 0.f, 0.f};
    }

    size_t rowoff = (size_t)h0 * 34 + wA;
    Tap12 TA, TB;
    load12(H1h, ((size_t)b * 8 + 0) * 1156 + rowoff + 35, kg, TA);
#pragma unroll
    for (int k0 = 0; k0 < 8; ++k0) {
        if (k0 < 7)
            load12(H1h, ((size_t)b * 8 + (k0 + 1)) * 1156 + rowoff + 35, kg,
                   (k0 & 1) ? TA : TB);
        f16x8 a0, a1;
        convg2((k0 & 1) ? TB : TA, DBh, DWh, k0, kg, a0, a1);
#pragma unroll
        for (int n = 0; n < 4; ++n) {
            f16x8 bf = *(const f16x8*)(W2T + ((size_t)(n * 16 + lr) * 256 + k0 * 32 + kg * 8));
            acc0[n] = __builtin_amdgcn_mfma_f32_16x16x32_f16(a0, bf, acc0[n], 0, 0, 0);
            acc1[n] = __builtin_amdgcn_mfma_f32_16x16x32_f16(a1, bf, acc1[n], 0, 0, 0);
        }
    }
    size_t ob0 = (size_t)b * 1024 + (size_t)h0 * 32;
#pragma unroll
    for (int n = 0; n < 4; ++n) {
        int c = n * 16 + lr;
        float b2v = B2[c];
#pragma unroll
        for (int reg = 0; reg < 4; ++reg) {
            int rowTok = w0 + kg * 4 + reg;
            size_t g0i = (ob0 + rowTok) * 64 + c;
            out[g0i] += acc0[n][reg] + b2v;
            size_t g1i = (ob0 + 32 + rowTok) * 64 + c;
            out[g1i] += acc1[n][reg] + b2v;
        }
    }
}

extern "C" void kernel_launch(void* const* d_in, const int* in_sizes, int n_in,
                              void* d_out, int out_size, void* d_ws, size_t ws_size,
                              hipStream_t stream) {
    const float* x = (const float*)d_in[0];
    const float* ln1_g = (const float*)d_in[1];
    const float* ln1_b = (const float*)d_in[2];
    const float* w_ll = (const float*)d_in[3];
    const float* w1 = (const float*)d_in[4];
    const float* w2 = (const float*)d_in[5];
    const float* b1 = (const float*)d_in[6];
    const float* b2 = (const float*)d_in[7];
    const float* ln2_g = (const float*)d_in[8];
    const float* ln2_b = (const float*)d_in[9];
    const float* lin1_w = (const float*)d_in[10];
    const float* lin1_b = (const float*)d_in[11];
    const float* dw_w = (const float*)d_in[12];
    const float* dw_b = (const float*)d_in[13];
    const float* lin2_w = (const float*)d_in[14];
    const float* lin2_b = (const float*)d_in[15];
    float* out = (float*)d_out;
    char* ws = (char*)d_ws;

    // Lifetimes (R17 layout, measured-best):
    //  Ah   [0, 33.5MB)     : LN1 out; dead after k_fwd. Reused: mlp tables, Yh, H1h.
    //  HSr  [64MiB, 112MiB) : live k_fwd..k_inv.
    //  HSi  [160MiB, 208MiB): live k_fwd..k_inv. Reused after inv: leff tables.
    //  Yh   [0, 33.5MB)     : k_inv writes, k_addt reads; dead before k_halo.
    //  H1h  [0, 144.5MiB)   : k_halo/k_leff1m write, k_leff2m reads.
    __half* Ah = (__half*)ws;
    __half* HSr = (__half*)(ws + 67108864);
    __half* HSi = (__half*)(ws + 167772160);
    float* LL = out;
    __half* Yh = (__half*)ws;
    __half* H1h = (__half*)ws;
    __half* W1cr = (__half*)(ws);
    __half* W1ci = (__half*)(ws + 4096);
    __half* W2cr = (__half*)(ws + 8192);
    __half* W2ci = (__half*)(ws + 12288);
    char* wtab = ws + 167772160;
    __half2* DWh = (__half2*)(wtab);
    __half2* DBh = (__half2*)(wtab + 8192);
    __half* W2T = (__half*)(wtab + 12288);
    __half* W1T = (__half*)(wtab + 49152);

    k_ln1_t<<<dim3(4096), dim3(256), 0, stream>>>(x, ln1_g, ln1_b, Ah);
    k_fwd<<<dim3(16384), dim3(256), 0, stream>>>(Ah, w_ll, LL, HSr, HSi);
    k_prep_mlp<<<dim3(8), dim3(256), 0, stream>>>(w1, w2, W1cr, W1ci, W2cr, W2ci);
    k_mlpm<<<dim3(1536), dim3(256), 0, stream>>>(HSr, HSi, W1cr, W1ci, W2cr, W2ci, b1, b2);
    k_inv<<<dim3(16384), dim3(256), 0, stream>>>(LL, HSr, HSi, Yh);
    k_addt<<<dim3(4096), dim3(256), 0, stream>>>(Yh, x, out);
    k_halo<<<dim3(2048), dim3(256), 0, stream>>>((__half2*)H1h);
    k_prep_leff<<<dim3(72), dim3(256), 0, stream>>>(dw_w, dw_b, lin2_w, lin1_w,
                                                    DWh, DBh, W2T, W1T);
    k_leff1m<<<dim3(4096), dim3(256), 0, stream>>>(out, ln2_g, ln2_b, W1T, lin1_b, H1h);
    k_leff2m<<<dim3(2048), dim3(256), 0, stream>>>(H1h, DWh, DBh, W2T, b2, out);
}

// Round 22
// 443.880 us; speedup vs baseline: 1.1096x; 1.0239x over previous
//
#include <hip/hip_runtime.h>
#include <hip/hip_fp16.h>
#include <math.h>

#define ISQ2 0.70710678118654752440f

typedef _Float16 f16x8 __attribute__((ext_vector_type(8)));
typedef __attribute__((ext_vector_type(4))) float f32x4;

static __device__ __constant__ float H0c[13] = {
    -0.0017578f, 0.0f, 0.0222656f, -0.046875f, -0.0482422f, 0.296875f,
    0.5554688f, 0.296875f, -0.0482422f, -0.046875f, 0.0222656f, 0.0f, -0.0017578f};
static __device__ __constant__ float H1c[19] = {
    -7.06e-05f, 0.0f, 0.0013419f, -0.0018834f, -0.0071568f, 0.023856f,
    0.0556431f, -0.0516881f, -0.2997576f, 0.5594308f, -0.2997576f, -0.0516881f,
    0.0556431f, 0.023856f, -0.0071568f, -0.0018834f, 0.0013419f, 0.0f, -7.06e-05f};

__device__ __forceinline__ int refl32(int i) {
    if (i < 0) i = -1 - i;
    if (i > 31) i = 63 - i;
    return i;
}

// tanh-form GELU with hardware-rcp (v_rcp_f32, ~1ulp): |err| < ~1e-3 vs exact
__device__ __forceinline__ float gelu_fast(float x) {
    float u = x * (0.7978845608f + 0.0356774081f * x * x);
    float e = __expf(-2.0f * fabsf(u));
    float t = 1.0f - 2.0f * e * __builtin_amdgcn_rcpf(1.0f + e);
    t = copysignf(t, u);
    return 0.5f * x * (1.0f + t);
}

__device__ __forceinline__ __half2 u2h2(unsigned int u) {
    union { unsigned int u; __half2 h; } c;
    c.u = u;
    return c.h;
}

// ---------------- K1: LN1 + transpose (B,N,C)->(B,C,32,32) fp16 --------------
__global__ __launch_bounds__(256) void k_ln1_t(const float* __restrict__ x,
                                               const float* __restrict__ g,
                                               const float* __restrict__ be,
                                               __half* __restrict__ Ah) {
    __shared__ float sx[64][65];
    __shared__ float rs[64][4], rq[64][4];
    __shared__ float sm[64], sv[64];
    int b = blockIdx.x >> 4;
    int n0 = (blockIdx.x & 15) << 6;
    int tid = threadIdx.x;
    const float* xp = x + ((size_t)b * 1024 + n0) * 64;
#pragma unroll
    for (int rep = 0; rep < 16; ++rep) {
        int idx = rep * 256 + tid;
        sx[idx >> 6][idx & 63] = xp[idx];
    }
    __syncthreads();
    {
        int i = tid >> 2, q = tid & 3;
        float s = 0.f, ss = 0.f;
#pragma unroll
        for (int d = 0; d < 16; ++d) {
            float v = sx[i][q * 16 + d];
            s += v; ss += v * v;
        }
        rs[i][q] = s; rq[i][q] = ss;
    }
    __syncthreads();
    if (tid < 64) {
        float s = rs[tid][0] + rs[tid][1] + rs[tid][2] + rs[tid][3];
        float ss = rq[tid][0] + rq[tid][1] + rq[tid][2] + rq[tid][3];
        float m = s * (1.f / 64.f);
        float v = ss * (1.f / 64.f) - m * m;
        sm[tid] = m;
        sv[tid] = rsqrtf(v + 1e-5f);
    }
    __syncthreads();
#pragma unroll
    for (int rep = 0; rep < 16; ++rep) {
        int idx = rep * 256 + tid;
        int c = idx >> 6, i = idx & 63;
        float val = (sx[i][c] - sm[i]) * sv[i] * g[c] + be[c];
        Ah[((size_t)(b * 64 + c)) * 1024 + n0 + i] = __float2half(val);
    }
}

// ---------------- K2: forward DTCWT (fp16 in/out incl. LL) -------------------
__global__ __launch_bounds__(256, 4) void k_fwd(const __half* __restrict__ Ah,
                                                const float* __restrict__ wll,
                                                __half* __restrict__ LLh,
                                                __half* __restrict__ HSr,
                                                __half* __restrict__ HSi) {
    __shared__ float sx[32][52];
    __shared__ float slo[50][34];
    __shared__ float shi[50][34];
    int bc = blockIdx.x;
    int c = bc & 63;
    int tid = threadIdx.x;
    int hA = tid >> 3, w0r = (tid & 7) * 4;
    {
        const __half2* ap2 = (const __half2*)(Ah + (size_t)bc * 1024);
        __half2 v01 = ap2[tid * 2], v23 = ap2[tid * 2 + 1];
        sx[hA][w0r + 9] = __low2float(v01);
        sx[hA][w0r + 10] = __high2float(v01);
        sx[hA][w0r + 11] = __low2float(v23);
        sx[hA][w0r + 12] = __high2float(v23);
    }
    __syncthreads();
    for (int i = tid; i < 576; i += 256) {
        int h = i / 18, j = i - (i / 18) * 18;
        int wp = (j < 9) ? (j - 9) : (23 + j);
        sx[h][wp + 9] = sx[h][refl32(wp) + 9];
    }
    __syncthreads();
    {
        float ws[22];
#pragma unroll
        for (int t = 0; t < 22; ++t) ws[t] = sx[hA][w0r + t];
        float lo[4] = {0.f, 0.f, 0.f, 0.f}, hi[4] = {0.f, 0.f, 0.f, 0.f};
#pragma unroll
        for (int k = 0; k < 19; ++k)
#pragma unroll
            for (int j = 0; j < 4; ++j) hi[j] += H1c[k] * ws[j + k];
#pragma unroll
        for (int k = 0; k < 13; ++k)
#pragma unroll
            for (int j = 0; j < 4; ++j) lo[j] += H0c[k] * ws[j + k + 3];
#pragma unroll
        for (int j = 0; j < 4; ++j) {
            slo[hA + 9][w0r + j] = lo[j];
            shi[hA + 9][w0r + j] = hi[j];
        }
    }
    __syncthreads();
    for (int i = tid; i < 576; i += 256) {
        int j = i >> 5, w = i & 31;
        int hp = (j < 9) ? (j - 9) : (23 + j);
        int hs = refl32(hp);
        slo[hp + 9][w] = slo[hs + 9][w];
        shi[hp + 9][w] = shi[hs + 9][w];
    }
    __syncthreads();
    {
        int wL = tid & 31, h0 = (tid >> 5) * 4;
        float cs[16];
#pragma unroll
        for (int t = 0; t < 16; ++t) cs[t] = slo[h0 + 3 + t][wL];
#pragma unroll
        for (int j = 0; j < 4; ++j) {
            float acc = 0.f;
#pragma unroll
            for (int k = 0; k < 13; ++k) acc += H0c[k] * cs[j + k];
            int p = (h0 + j) * 32 + wL;
            LLh[(size_t)bc * 1024 + p] = __float2half(acc * wll[c * 1024 + p]);
        }
    }
    {
        int i = tid >> 4, j = tid & 15;
        size_t base = (size_t)bc * 1536 + tid;
        float a, bb, cc2, dd;
        {
            float2 sl[20];
#pragma unroll
            for (int t = 0; t < 20; ++t) sl[t] = *(const float2*)&slo[2 * i + t][2 * j];
            a = bb = cc2 = dd = 0.f;
#pragma unroll
            for (int k = 0; k < 19; ++k) {
                a += H1c[k] * sl[k].x;
                bb += H1c[k] * sl[k].y;
                cc2 += H1c[k] * sl[k + 1].x;
                dd += H1c[k] * sl[k + 1].y;
            }
            HSr[base + 0 * 256] = __float2half((a - dd) * ISQ2);
            HSi[base + 0 * 256] = __float2half((bb + cc2) * ISQ2);
            HSr[base + 5 * 256] = __float2half((a + dd) * ISQ2);
            HSi[base + 5 * 256] = __float2half((bb - cc2) * ISQ2);
        }
        {
            float2 sh[20];
#pragma unroll
            for (int t = 0; t < 20; ++t) sh[t] = *(const float2*)&shi[2 * i + t][2 * j];
            a = bb = cc2 = dd = 0.f;
#pragma unroll
            for (int k = 0; k < 19; ++k) {
                a += H1c[k] * sh[k].x;
                bb += H1c[k] * sh[k].y;
                cc2 += H1c[k] * sh[k + 1].x;
                dd += H1c[k] * sh[k + 1].y;
            }
            HSr[base + 1 * 256] = __float2half((a - dd) * ISQ2);
            HSi[base + 1 * 256] = __float2half((bb + cc2) * ISQ2);
            HSr[base + 4 * 256] = __float2half((a + dd) * ISQ2);
            HSi[base + 4 * 256] = __float2half((bb - cc2) * ISQ2);
            a = bb = cc2 = dd = 0.f;
#pragma unroll
            for (int k = 0; k < 13; ++k) {
                a += H0c[k] * sh[k + 3].x;
                bb += H0c[k] * sh[k + 3].y;
                cc2 += H0c[k] * sh[k + 4].x;
                dd += H0c[k] * sh[k + 4].y;
            }
            HSr[base + 2 * 256] = __float2half((a - dd) * ISQ2);
            HSi[base + 2 * 256] = __float2half((bb + cc2) * ISQ2);
            HSr[base + 3 * 256] = __float2half((a + dd) * ISQ2);
            HSi[base + 3 * 256] = __float2half((bb - cc2) * ISQ2);
        }
    }
}

// ---------------- K2b: prep complex-MLP fp16 B-frags (runs AFTER k_fwd) -------
__global__ __launch_bounds__(256) void k_prep_mlp(const float* __restrict__ mw1,
                                                  const float* __restrict__ mw2,
                                                  __half* __restrict__ W1cr,
                                                  __half* __restrict__ W1ci,
                                                  __half* __restrict__ W2cr,
                                                  __half* __restrict__ W2ci) {
    int gid = blockIdx.x * 256 + threadIdx.x;
    int stride = gridDim.x * 256;
    for (int i = gid; i < 2048; i += stride) {
        int q = i >> 9, rest = i & 511;
        int n = rest >> 5, k = rest & 31;
        if (k < 16) {
            W1cr[i] = __float2half(mw1[q * 256 + k * 16 + n]);
            W1ci[i] = __float2half(mw1[1024 + q * 256 + k * 16 + n]);
            W2cr[i] = __float2half(mw2[q * 256 + k * 16 + n]);
            W2ci[i] = __float2half(mw2[1024 + q * 256 + k * 16 + n]);
        } else {
            W1cr[i] = __float2half(-mw1[1024 + q * 256 + (k - 16) * 16 + n]);
            W1ci[i] = __float2half(mw1[q * 256 + (k - 16) * 16 + n]);
            W2cr[i] = __float2half(-mw2[1024 + q * 256 + (k - 16) * 16 + n]);
            W2ci[i] = __float2half(mw2[q * 256 + (k - 16) * 16 + n]);
        }
    }
}

// ---------------- K3: complex block-MLP via MFMA, fp16 HS in/out --------------
__global__ __launch_bounds__(256) void k_mlpm(__half* __restrict__ HSr,
                                              __half* __restrict__ HSi,
                                              const __half* __restrict__ W1cr,
                                              const __half* __restrict__ W1ci,
                                              const __half* __restrict__ W2cr,
                                              const __half* __restrict__ W2ci,
                                              const float* __restrict__ b1,
                                              const float* __restrict__ b2) {
    __shared__ __half xh[4][64][40];
    int tid = threadIdx.x;
    int wid = tid >> 6, lane = tid & 63;
    int lr = lane & 15, kg = lane >> 4;
    int b = blockIdx.x / 6;
    int o = blockIdx.x - b * 6;
    size_t base = (size_t)b * 98304 + (size_t)o * 256;

#pragma unroll 1
    for (int q = 0; q < 4; ++q) {
#pragma unroll
        for (int mt = 0; mt < 4; ++mt) {
            int token0 = wid * 64 + mt * 16;
            const unsigned short* src =
                (const unsigned short*)((kg < 2) ? HSr : HSi);
            int c0 = q * 16 + (kg & 1) * 8;
            unsigned int u[4];
#pragma unroll
            for (int e = 0; e < 4; ++e) {
                unsigned int lo = src[base + (size_t)(c0 + 2 * e) * 1536 + token0 + lr];
                unsigned int hi = src[base + (size_t)(c0 + 2 * e + 1) * 1536 + token0 + lr];
                u[e] = lo | (hi << 16);
            }
            uint4 av = make_uint4(u[0], u[1], u[2], u[3]);
            f16x8 a = *(f16x8*)&av;
            f16x8 bfr = *(const f16x8*)(W1cr + q * 512 + lr * 32 + kg * 8);
            f16x8 bfi = *(const f16x8*)(W1ci + q * 512 + lr * 32 + kg * 8);
            f32x4 accr = (f32x4){0.f, 0.f, 0.f, 0.f};
            f32x4 acci = (f32x4){0.f, 0.f, 0.f, 0.f};
            accr = __builtin_amdgcn_mfma_f32_16x16x32_f16(a, bfr, accr, 0, 0, 0);
            acci = __builtin_amdgcn_mfma_f32_16x16x32_f16(a, bfi, acci, 0, 0, 0);
            float b1r = b1[q * 16 + lr];
            float b1i = b1[64 + q * 16 + lr];
#pragma unroll
            for (int reg = 0; reg < 4; ++reg) {
                int tl = mt * 16 + kg * 4 + reg;
                xh[wid][tl][lr] = __float2half(fmaxf(accr[reg] + b1r, 0.f));
                xh[wid][tl][16 + lr] = __float2half(fmaxf(acci[reg] + b1i, 0.f));
            }
        }
        __syncthreads();
#pragma unroll
        for (int mt = 0; mt < 4; ++mt) {
            f16x8 a = *(const f16x8*)&xh[wid][mt * 16 + lr][kg * 8];
            f16x8 bfr = *(const f16x8*)(W2cr + q * 512 + lr * 32 + kg * 8);
            f16x8 bfi = *(const f16x8*)(W2ci + q * 512 + lr * 32 + kg * 8);
            f32x4 accr = (f32x4){0.f, 0.f, 0.f, 0.f};
            f32x4 acci = (f32x4){0.f, 0.f, 0.f, 0.f};
            accr = __builtin_amdgcn_mfma_f32_16x16x32_f16(a, bfr, accr, 0, 0, 0);
            acci = __builtin_amdgcn_mfma_f32_16x16x32_f16(a, bfi, acci, 0, 0, 0);
            float b2r = b2[q * 16 + lr];
            float b2i = b2[64 + q * 16 + lr];
            size_t cb = base + (size_t)(q * 16 + lr) * 1536 + wid * 64 + mt * 16 + kg * 4;
#pragma unroll
            for (int reg = 0; reg < 4; ++reg) {
                HSr[cb + reg] = __float2half(accr[reg] + b2r);
                HSi[cb + reg] = __float2half(acci[reg] + b2i);
            }
        }
        __syncthreads();
    }
}

// ---------------- K4: inverse DTCWT (fp16 in/out incl. LL) --------------------
__global__ __launch_bounds__(256, 4) void k_inv(const __half* __restrict__ LLh,
                                                const __half* __restrict__ HSr,
                                                const __half* __restrict__ HSi,
                                                __half* __restrict__ Yh) {
    __shared__ float sll[50][34], slh[50][34], shl[50][34], shh[50][34];
    __shared__ float slo[32][52], shi[32][52];
    int bc = blockIdx.x;
    int tid = threadIdx.x;
    int hA = tid >> 3, w0r = (tid & 7) * 4;
    {
        const __half2* lp2 = (const __half2*)(LLh + (size_t)bc * 1024);
        __half2 v01 = lp2[tid * 2], v23 = lp2[tid * 2 + 1];
        sll[hA + 9][w0r] = __low2float(v01);
        sll[hA + 9][w0r + 1] = __high2float(v01);
        sll[hA + 9][w0r + 2] = __low2float(v23);
        sll[hA + 9][w0r + 3] = __high2float(v23);
    }
    {
        int i = tid >> 4, j = tid & 15;
        int h0 = 2 * i + 9, w0 = 2 * j;
        size_t base = (size_t)bc * 1536 + tid;
        float o0r = __half2float(HSr[base + 0 * 256]), o0i = __half2float(HSi[base + 0 * 256]);
        float o1r = __half2float(HSr[base + 1 * 256]), o1i = __half2float(HSi[base + 1 * 256]);
        float o2r = __half2float(HSr[base + 2 * 256]), o2i = __half2float(HSi[base + 2 * 256]);
        float o3r = __half2float(HSr[base + 3 * 256]), o3i = __half2float(HSi[base + 3 * 256]);
        float o4r = __half2float(HSr[base + 4 * 256]), o4i = __half2float(HSi[base + 4 * 256]);
        float o5r = __half2float(HSr[base + 5 * 256]), o5i = __half2float(HSi[base + 5 * 256]);
        *(float2*)&slh[h0][w0] = make_float2((o0r + o5r) * ISQ2, (o0i + o5i) * ISQ2);
        *(float2*)&slh[h0 + 1][w0] = make_float2((o0i - o5i) * ISQ2, (o5r - o0r) * ISQ2);
        *(float2*)&shl[h0][w0] = make_float2((o2r + o3r) * ISQ2, (o2i + o3i) * ISQ2);
        *(float2*)&shl[h0 + 1][w0] = make_float2((o2i - o3i) * ISQ2, (o3r - o2r) * ISQ2);
        *(float2*)&shh[h0][w0] = make_float2((o1r + o4r) * ISQ2, (o1i + o4i) * ISQ2);
        *(float2*)&shh[h0 + 1][w0] = make_float2((o1i - o4i) * ISQ2, (o4r - o1r) * ISQ2);
    }
    __syncthreads();
    for (int i = tid; i < 576; i += 256) {
        int j = i >> 5, w = i & 31;
        int hp = (j < 9) ? (j - 9) : (23 + j);
        int hs = refl32(hp);
        sll[hp + 9][w] = sll[hs + 9][w];
        slh[hp + 9][w] = slh[hs + 9][w];
        shl[hp + 9][w] = shl[hs + 9][w];
        shh[hp + 9][w] = shh[hs + 9][w];
    }
    __syncthreads();
    {
        int wL = tid & 31, h0 = (tid >> 5) * 4;
        float w19[22], w13[16];
        float lo[4] = {0.f, 0.f, 0.f, 0.f}, hi[4] = {0.f, 0.f, 0.f, 0.f};
#pragma unroll
        for (int t = 0; t < 22; ++t) w19[t] = sll[h0 + t][wL];
#pragma unroll
        for (int k = 0; k < 19; ++k) {
            float g0 = (k & 1) ? H1c[k] : -H1c[k];
#pragma unroll
            for (int j = 0; j < 4; ++j) lo[j] += g0 * w19[j + k];
        }
#pragma unroll
        for (int t = 0; t < 16; ++t) w13[t] = slh[h0 + 3 + t][wL];
#pragma unroll
        for (int k = 0; k < 13; ++k) {
            float g1 = (k & 1) ? H0c[k] : -H0c[k];
#pragma unroll
            for (int j = 0; j < 4; ++j) lo[j] += g1 * w13[j + k];
        }
#pragma unroll
        for (int t = 0; t < 22; ++t) w19[t] = shl[h0 + t][wL];
#pragma unroll
        for (int k = 0; k < 19; ++k) {
            float g0 = (k & 1) ? H1c[k] : -H1c[k];
#pragma unroll
            for (int j = 0; j < 4; ++j) hi[j] += g0 * w19[j + k];
        }
#pragma unroll
        for (int t = 0; t < 16; ++t) w13[t] = shh[h0 + 3 + t][wL];
#pragma unroll
        for (int k = 0; k < 13; ++k) {
            float g1 = (k & 1) ? H0c[k] : -H0c[k];
#pragma unroll
            for (int j = 0; j < 4; ++j) hi[j] += g1 * w13[j + k];
        }
#pragma unroll
        for (int j = 0; j < 4; ++j) {
            slo[h0 + j][wL + 9] = lo[j];
            shi[h0 + j][wL + 9] = hi[j];
        }
    }
    __syncthreads();
    for (int i = tid; i < 576; i += 256) {
        int h = i / 18, j = i - (i / 18) * 18;
        int wp = (j < 9) ? (j - 9) : (23 + j);
        int ws2 = refl32(wp);
        slo[h][wp + 9] = slo[h][ws2 + 9];
        shi[h][wp + 9] = shi[h][ws2 + 9];
    }
    __syncthreads();
    {
        float rw[22], rh[16];
#pragma unroll
        for (int t = 0; t < 22; ++t) rw[t] = slo[hA][w0r + t];
#pragma unroll
        for (int t = 0; t < 16; ++t) rh[t] = shi[hA][w0r + 3 + t];
        float y[4] = {0.f, 0.f, 0.f, 0.f};
#pragma unroll
        for (int k = 0; k < 19; ++k) {
            float g0 = (k & 1) ? H1c[k] : -H1c[k];
#pragma unroll
            for (int j = 0; j < 4; ++j) y[j] += g0 * rw[j + k];
        }
#pragma unroll
        for (int k = 0; k < 13; ++k) {
            float g1 = (k & 1) ? H0c[k] : -H0c[k];
#pragma unroll
            for (int j = 0; j < 4; ++j) y[j] += g1 * rh[j + k];
        }
        __half2 y01 = __floats2half2_rn(y[0], y[1]);
        __half2 y23 = __floats2half2_rn(y[2], y[3]);
        uint2 pk;
        pk.x = *(unsigned int*)&y01;
        pk.y = *(unsigned int*)&y23;
        *(uint2*)(Yh + (size_t)bc * 1024 + hA * 32 + w0r) = pk;
    }
}

// ---------------- K4b: X1 = x + Y^T -> X1h fp16 (B,N,C) ----------------------
__global__ __launch_bounds__(256) void k_addt(const __half* __restrict__ Yh,
                                              const float* __restrict__ x,
                                              __half* __restrict__ X1h) {
    __shared__ float sy[64][65];
    int b = blockIdx.x >> 4;
    int n0 = (blockIdx.x & 15) << 6;
    int tid = threadIdx.x;
#pragma unroll
    for (int rep = 0; rep < 16; ++rep) {
        int idx = rep * 256 + tid;
        int c = idx >> 6, i = idx & 63;
        sy[c][i] = __half2float(Yh[((size_t)(b * 64 + c)) * 1024 + n0 + i]);
    }
    __syncthreads();
#pragma unroll
    for (int rep = 0; rep < 16; ++rep) {
        int idx = rep * 256 + tid;
        int i = idx >> 6, c = idx & 63;
        size_t gi = ((size_t)b * 1024 + n0 + i) * 64 + c;
        X1h[gi] = __float2half(x[gi] + sy[c][i]);
    }
}

// ---------------- K4c: zero the halo of padded H1 (b,k0,34,34,32) fp16 --------
__global__ __launch_bounds__(256) void k_halo(__half2* __restrict__ H1h2) {
    int img = blockIdx.x;  // 2048
    __half2* base = H1h2 + (size_t)img * 1156 * 16;
    __half2 z = __floats2half2_rn(0.f, 0.f);
    for (int idx = threadIdx.x; idx < 2112; idx += 256) {
        int pos = idx >> 4, c = idx & 15;
        int p2;
        if (pos < 34) p2 = pos;
        else if (pos < 68) p2 = 33 * 34 + (pos - 34);
        else if (pos < 100) p2 = (pos - 68 + 1) * 34;
        else p2 = (pos - 100 + 1) * 34 + 33;
        base[p2 * 16 + c] = z;
    }
}

// ---------------- K4d: prep LeFF fp16 weight tables (runs AFTER k_inv) --------
__global__ __launch_bounds__(256) void k_prep_leff(const float* __restrict__ DW,
                                                   const float* __restrict__ DB,
                                                   const float* __restrict__ W2,
                                                   const float* __restrict__ W1,
                                                   __half2* __restrict__ DWh,
                                                   __half2* __restrict__ DBh,
                                                   __half* __restrict__ W2T,
                                                   __half* __restrict__ W1T) {
    int gid = blockIdx.x * 256 + threadIdx.x;
    int stride = gridDim.x * 256;
    for (int i = gid; i < 1152; i += stride) {
        int tap = i >> 7, pr = i & 127;
        DWh[i] = __floats2half2_rn(DW[(2 * pr) * 9 + tap], DW[(2 * pr + 1) * 9 + tap]);
    }
    for (int i = gid; i < 128; i += stride)
        DBh[i] = __floats2half2_rn(DB[2 * i], DB[2 * i + 1]);
    for (int i = gid; i < 16384; i += stride) {
        int n = i >> 8, k = i & 255;
        W2T[i] = __float2half(W2[k * 64 + n]);
    }
    for (int i = gid; i < 16384; i += stride)
        W1T[i] = __float2half(W1[(i & 63) * 256 + (i >> 6)]);
}

// ---------------- K5: LN2 + lin1(MFMA fp16) + GELU -> H1 fp16 padded ----------
__global__ __launch_bounds__(256) void k_leff1m(const __half* __restrict__ X1h,
                                                const float* __restrict__ g2,
                                                const float* __restrict__ be2,
                                                const __half* __restrict__ W1T,
                                                const float* __restrict__ B1,
                                                __half* __restrict__ H1h) {
    __shared__ __half xnh[64][72];
    int tid = threadIdx.x;
    int wid = tid >> 6, lane = tid & 63;
    int lr = lane & 15, kg = lane >> 4;
    int bimg = blockIdx.x >> 4;
    int hw0 = (blockIdx.x & 15) << 6;
    size_t tok0 = (size_t)blockIdx.x * 64;
    int ltok = wid * 16 + lr;
    {
        const uint4* xp = (const uint4*)(X1h + (tok0 + ltok) * 64 + kg * 16);
        uint4 q0 = xp[0], q1 = xp[1];
        unsigned int uu[8] = {q0.x, q0.y, q0.z, q0.w, q1.x, q1.y, q1.z, q1.w};
        float vv[16];
#pragma unroll
        for (int i = 0; i < 8; ++i) {
            __half2 h = u2h2(uu[i]);
            vv[2 * i] = __low2float(h);
            vv[2 * i + 1] = __high2float(h);
        }
        float s = 0.f, ss = 0.f;
#pragma unroll
        for (int i = 0; i < 16; ++i) {
            s += vv[i];
            ss += vv[i] * vv[i];
        }
        s += __shfl_xor(s, 16, 64);
        ss += __shfl_xor(ss, 16, 64);
        s += __shfl_xor(s, 32, 64);
        ss += __shfl_xor(ss, 32, 64);
        float m = s * (1.f / 64.f);
        float var = ss * (1.f / 64.f) - m * m;
        float rstd = rsqrtf(var + 1e-5f);
        unsigned int u[8];
#pragma unroll
        for (int i = 0; i < 8; ++i) {
            int d = kg * 16 + 2 * i;
            float a0 = (vv[2 * i] - m) * rstd * g2[d] + be2[d];
            float a1 = (vv[2 * i + 1] - m) * rstd * g2[d + 1] + be2[d + 1];
            __half2 hh = __floats2half2_rn(a0, a1);
            u[i] = *(unsigned int*)&hh;
        }
        *(uint4*)&xnh[ltok][kg * 16] = make_uint4(u[0], u[1], u[2], u[3]);
        *(uint4*)&xnh[ltok][kg * 16 + 8] = make_uint4(u[4], u[5], u[6], u[7]);
    }
    __syncthreads();
    f32x4 acc[16];
#pragma unroll
    for (int n = 0; n < 16; ++n) acc[n] = (f32x4){0.f, 0.f, 0.f, 0.f};
#pragma unroll
    for (int k0 = 0; k0 < 2; ++k0) {
        f16x8 a = *(const f16x8*)&xnh[wid * 16 + lr][k0 * 32 + kg * 8];
#pragma unroll
        for (int n = 0; n < 16; ++n) {
            f16x8 bf = *(const f16x8*)(W1T + (size_t)(n * 16 + lr) * 64 + k0 * 32 + kg * 8);
            acc[n] = __builtin_amdgcn_mfma_f32_16x16x32_f16(a, bf, acc[n], 0, 0, 0);
        }
    }
#pragma unroll
    for (int n = 0; n < 16; ++n) {
        int hid = n * 16 + lr;
        float bb = B1[hid];
        size_t cb = ((size_t)bimg * 8 + (hid >> 5)) * 1156;
        int cl = hid & 31;
#pragma unroll
        for (int reg = 0; reg < 4; ++reg) {
            int token = wid * 16 + kg * 4 + reg;
            int hw = hw0 + token;
            int h = hw >> 5, w = hw & 31;
            H1h[(cb + (size_t)(h + 1) * 34 + (w + 1)) * 32 + cl] =
                __float2half(gelu_fast(acc[n][reg] + bb));
        }
    }
}

// ---------------- K6: fused dwconv+GELU+lin2(MFMA), 2 rows/wave ---------------
struct Tap12 { uint4 v[12]; };

__device__ __forceinline__ void load12(const __half* H1h, size_t pb, int kg, Tap12& T) {
    const __half2* p = (const __half2*)(H1h + pb * 32) + kg * 4;
#pragma unroll
    for (int r = 0; r < 4; ++r)
#pragma unroll
        for (int dc = 0; dc < 3; ++dc)
            T.v[r * 3 + dc] = *(const uint4*)(p + ((r - 1) * 34 + (dc - 1)) * 16);
}

__device__ __forceinline__ void convg2(const Tap12& T,
                                       const __half2* __restrict__ DBh,
                                       const __half2* __restrict__ DWh,
                                       int k0, int kg, f16x8& a0out, f16x8& a1out) {
    const __half2* dbp = DBh + k0 * 16 + kg * 4;
    __half2 c00 = dbp[0], c01 = dbp[1], c02 = dbp[2], c03 = dbp[3];
    __half2 c10 = c00, c11 = c01, c12 = c02, c13 = c03;
#pragma unroll
    for (int dr = 0; dr < 3; ++dr) {
#pragma unroll
        for (int dc = 0; dc < 3; ++dc) {
            const __half2* wp = DWh + (dr * 3 + dc) * 128 + k0 * 16 + kg * 4;
            __half2 w0 = wp[0], w1 = wp[1], w2 = wp[2], w3 = wp[3];
            const uint4& t0 = T.v[dr * 3 + dc];
            const uint4& t1 = T.v[(dr + 1) * 3 + dc];
            c00 = __hfma2(u2h2(t0.x), w0, c00);
            c01 = __hfma2(u2h2(t0.y), w1, c01);
            c02 = __hfma2(u2h2(t0.z), w2, c02);
            c03 = __hfma2(u2h2(t0.w), w3, c03);
            c10 = __hfma2(u2h2(t1.x), w0, c10);
            c11 = __hfma2(u2h2(t1.y), w1, c11);
            c12 = __hfma2(u2h2(t1.z), w2, c12);
            c13 = __hfma2(u2h2(t1.w), w3, c13);
        }
    }
    __half2 o0 = __floats2half2_rn(gelu_fast(__low2float(c00)), gelu_fast(__high2float(c00)));
    __half2 o1 = __floats2half2_rn(gelu_fast(__low2float(c01)), gelu_fast(__high2float(c01)));
    __half2 o2 = __floats2half2_rn(gelu_fast(__low2float(c02)), gelu_fast(__high2float(c02)));
    __half2 o3 = __floats2half2_rn(gelu_fast(__low2float(c03)), gelu_fast(__high2float(c03)));
    uint4 av0 = make_uint4(*(unsigned int*)&o0, *(unsigned int*)&o1,
                           *(unsigned int*)&o2, *(unsigned int*)&o3);
    a0out = *(f16x8*)&av0;
    o0 = __floats2half2_rn(gelu_fast(__low2float(c10)), gelu_fast(__high2float(c10)));
    o1 = __floats2half2_rn(gelu_fast(__low2float(c11)), gelu_fast(__high2float(c11)));
    o2 = __floats2half2_rn(gelu_fast(__low2float(c12)), gelu_fast(__high2float(c12)));
    o3 = __floats2half2_rn(gelu_fast(__low2float(c13)), gelu_fast(__high2float(c13)));
    uint4 av1 = make_uint4(*(unsigned int*)&o0, *(unsigned int*)&o1,
                           *(unsigned int*)&o2, *(unsigned int*)&o3);
    a1out = *(f16x8*)&av1;
}

__global__ __launch_bounds__(256, 3) void k_leff2m(const __half* __restrict__ H1h,
                                                   const __half2* __restrict__ DWh,
                                                   const __half2* __restrict__ DBh,
                                                   const __half* __restrict__ W2T,
                                                   const float* __restrict__ B2,
                                                   const __half* __restrict__ X1h,
                                                   float* __restrict__ out) {
    int tid = threadIdx.x;
    int wid = tid >> 6, lane = tid & 63;
    int mt = blockIdx.x * 4 + wid;   // 0..8191
    int b = mt >> 5;
    int rem = mt & 31;
    int h0 = (rem >> 1) * 2;
    int w0 = (rem & 1) << 4;
    int lr = lane & 15, kg = lane >> 4;
    int wA = w0 + lr;

    f32x4 acc0[4], acc1[4];
#pragma unroll
    for (int n = 0; n < 4; ++n) {
        acc0[n] = (f32x4){0.f, 0.f, 0.f, 0.f};
        acc1[n] = (f32x4){0.f, 0.f, 0.f, 0.f};
    }

    size_t rowoff = (size_t)h0 * 34 + wA;
    Tap12 TA, TB;
    load12(H1h, ((size_t)b * 8 + 0) * 1156 + rowoff + 35, kg, TA);
#pragma unroll
    for (int k0 = 0; k0 < 8; ++k0) {
        if (k0 < 7)
            load12(H1h, ((size_t)b * 8 + (k0 + 1)) * 1156 + rowoff + 35, kg,
                   (k0 & 1) ? TA : TB);
        f16x8 a0, a1;
        convg2((k0 & 1) ? TB : TA, DBh, DWh, k0, kg, a0, a1);
#pragma unroll
        for (int n = 0; n < 4; ++n) {
            f16x8 bf = *(const f16x8*)(W2T + ((size_t)(n * 16 + lr) * 256 + k0 * 32 + kg * 8));
            acc0[n] = __builtin_amdgcn_mfma_f32_16x16x32_f16(a0, bf, acc0[n], 0, 0, 0);
            acc1[n] = __builtin_amdgcn_mfma_f32_16x16x32_f16(a1, bf, acc1[n], 0, 0, 0);
        }
    }
    size_t ob0 = (size_t)b * 1024 + (size_t)h0 * 32;
#pragma unroll
    for (int n = 0; n < 4; ++n) {
        int c = n * 16 + lr;
        float b2v = B2[c];
#pragma unroll
        for (int reg = 0; reg < 4; ++reg) {
            int rowTok = w0 + kg * 4 + reg;
            size_t g0i = (ob0 + rowTok) * 64 + c;
            out[g0i] = __half2float(X1h[g0i]) + acc0[n][reg] + b2v;
            size_t g1i = (ob0 + 32 + rowTok) * 64 + c;
            out[g1i] = __half2float(X1h[g1i]) + acc1[n][reg] + b2v;
        }
    }
}

extern "C" void kernel_launch(void* const* d_in, const int* in_sizes, int n_in,
                              void* d_out, int out_size, void* d_ws, size_t ws_size,
                              hipStream_t stream) {
    const float* x = (const float*)d_in[0];
    const float* ln1_g = (const float*)d_in[1];
    const float* ln1_b = (const float*)d_in[2];
    const float* w_ll = (const float*)d_in[3];
    const float* w1 = (const float*)d_in[4];
    const float* w2 = (const float*)d_in[5];
    const float* b1 = (const float*)d_in[6];
    const float* b2 = (const float*)d_in[7];
    const float* ln2_g = (const float*)d_in[8];
    const float* ln2_b = (const float*)d_in[9];
    const float* lin1_w = (const float*)d_in[10];
    const float* lin1_b = (const float*)d_in[11];
    const float* dw_w = (const float*)d_in[12];
    const float* dw_b = (const float*)d_in[13];
    const float* lin2_w = (const float*)d_in[14];
    const float* lin2_b = (const float*)d_in[15];
    float* out = (float*)d_out;
    char* ws = (char*)d_ws;

    // Lifetimes:
    //  Ah   [0, 33.5MB)       : LN1 out; dead after k_fwd. Reused: mlp tables, Yh, H1h.
    //  HSr  [64MiB, 112MiB)   : live k_fwd..k_inv.
    //  HSi  [160MiB, 208MiB)  : live k_fwd..k_inv. Reused after inv: leff tables.
    //  LLh  [208MiB, +33.5MB) : k_fwd writes, k_inv reads; tail untouched by HS.
    //  Yh   [0, 33.5MB)       : k_inv writes, k_addt reads; dead before k_halo.
    //  X1h  [208MiB, +33.5MB) : k_addt writes (after inv; LLh dead), read by
    //                           k_leff1m and k_leff2m. No overlap with H1h/wtab.
    //  H1h  [0, 144.5MiB)     : k_halo/k_leff1m write, k_leff2m reads.
    __half* Ah = (__half*)ws;
    __half* HSr = (__half*)(ws + 67108864);
    __half* HSi = (__half*)(ws + 167772160);
    __half* LLh = (__half*)(ws + 218103808);
    __half* Yh = (__half*)ws;
    __half* X1h = (__half*)(ws + 218103808);
    __half* H1h = (__half*)ws;
    __half* W1cr = (__half*)(ws);
    __half* W1ci = (__half*)(ws + 4096);
    __half* W2cr = (__half*)(ws + 8192);
    __half* W2ci = (__half*)(ws + 12288);
    char* wtab = ws + 167772160;
    __half2* DWh = (__half2*)(wtab);
    __half2* DBh = (__half2*)(wtab + 8192);
    __half* W2T = (__half*)(wtab + 12288);
    __half* W1T = (__half*)(wtab + 49152);

    k_ln1_t<<<dim3(4096), dim3(256), 0, stream>>>(x, ln1_g, ln1_b, Ah);
    k_fwd<<<dim3(16384), dim3(256), 0, stream>>>(Ah, w_ll, LLh, HSr, HSi);
    k_prep_mlp<<<dim3(8), dim3(256), 0, stream>>>(w1, w2, W1cr, W1ci, W2cr, W2ci);
    k_mlpm<<<dim3(1536), dim3(256), 0, stream>>>(HSr, HSi, W1cr, W1ci, W2cr, W2ci, b1, b2);
    k_inv<<<dim3(16384), dim3(256), 0, stream>>>(LLh, HSr, HSi, Yh);
    k_addt<<<dim3(4096), dim3(256), 0, stream>>>(Yh, x, X1h);
    k_halo<<<dim3(2048), dim3(256), 0, stream>>>((__half2*)H1h);
    k_prep_leff<<<dim3(72), dim3(256), 0, stream>>>(dw_w, dw_b, lin2_w, lin1_w,
                                                    DWh, DBh, W2T, W1T);
    k_leff1m<<<dim3(4096), dim3(256), 0, stream>>>(X1h, ln2_g, ln2_b, W1T, lin1_b, H1h);
    k_leff2m<<<dim3(2048), dim3(256), 0, stream>>>(H1h, DWh, DBh, W2T, b2, X1h, out);
}

// Round 23
// 440.439 us; speedup vs baseline: 1.1183x; 1.0078x over previous
//
#include <hip/hip_runtime.h>
#include <hip/hip_fp16.h>
#include <math.h>

#define ISQ2 0.70710678118654752440f

typedef _Float16 f16x8 __attribute__((ext_vector_type(8)));
typedef __attribute__((ext_vector_type(4))) float f32x4;

static __device__ __constant__ float H0c[13] = {
    -0.0017578f, 0.0f, 0.0222656f, -0.046875f, -0.0482422f, 0.296875f,
    0.5554688f, 0.296875f, -0.0482422f, -0.046875f, 0.0222656f, 0.0f, -0.0017578f};
static __device__ __constant__ float H1c[19] = {
    -7.06e-05f, 0.0f, 0.0013419f, -0.0018834f, -0.0071568f, 0.023856f,
    0.0556431f, -0.0516881f, -0.2997576f, 0.5594308f, -0.2997576f, -0.0516881f,
    0.0556431f, 0.023856f, -0.0071568f, -0.0018834f, 0.0013419f, 0.0f, -7.06e-05f};

__device__ __forceinline__ int refl32(int i) {
    if (i < 0) i = -1 - i;
    if (i > 31) i = 63 - i;
    return i;
}

// tanh-form GELU with hardware-rcp (v_rcp_f32, ~1ulp): |err| < ~1e-3 vs exact
__device__ __forceinline__ float gelu_fast(float x) {
    float u = x * (0.7978845608f + 0.0356774081f * x * x);
    float e = __expf(-2.0f * fabsf(u));
    float t = 1.0f - 2.0f * e * __builtin_amdgcn_rcpf(1.0f + e);
    t = copysignf(t, u);
    return 0.5f * x * (1.0f + t);
}

__device__ __forceinline__ __half2 u2h2(unsigned int u) {
    union { unsigned int u; __half2 h; } c;
    c.u = u;
    return c.h;
}

// ---------------- K1: LN1 + transpose (B,N,C)->(B,C,32,32) fp16 --------------
__global__ __launch_bounds__(256) void k_ln1_t(const float* __restrict__ x,
                                               const float* __restrict__ g,
                                               const float* __restrict__ be,
                                               __half* __restrict__ Ah) {
    __shared__ float sx[64][65];
    __shared__ float rs[64][4], rq[64][4];
    __shared__ float sm[64], sv[64];
    int b = blockIdx.x >> 4;
    int n0 = (blockIdx.x & 15) << 6;
    int tid = threadIdx.x;
    const float* xp = x + ((size_t)b * 1024 + n0) * 64;
#pragma unroll
    for (int rep = 0; rep < 4; ++rep) {
        int idx = rep * 1024 + tid * 4;
        float4 v = *(const float4*)(xp + idx);
        int r = idx >> 6, c = idx & 63;
        sx[r][c] = v.x;
        sx[r][c + 1] = v.y;
        sx[r][c + 2] = v.z;
        sx[r][c + 3] = v.w;
    }
    __syncthreads();
    {
        int i = tid >> 2, q = tid & 3;
        float s = 0.f, ss = 0.f;
#pragma unroll
        for (int d = 0; d < 16; ++d) {
            float v = sx[i][q * 16 + d];
            s += v; ss += v * v;
        }
        rs[i][q] = s; rq[i][q] = ss;
    }
    __syncthreads();
    if (tid < 64) {
        float s = rs[tid][0] + rs[tid][1] + rs[tid][2] + rs[tid][3];
        float ss = rq[tid][0] + rq[tid][1] + rq[tid][2] + rq[tid][3];
        float m = s * (1.f / 64.f);
        float v = ss * (1.f / 64.f) - m * m;
        sm[tid] = m;
        sv[tid] = rsqrtf(v + 1e-5f);
    }
    __syncthreads();
#pragma unroll
    for (int rep = 0; rep < 16; ++rep) {
        int idx = rep * 256 + tid;
        int c = idx >> 6, i = idx & 63;
        float val = (sx[i][c] - sm[i]) * sv[i] * g[c] + be[c];
        Ah[((size_t)(b * 64 + c)) * 1024 + n0 + i] = __float2half(val);
    }
}

// ---------------- K2: forward DTCWT (fp16 in/out incl. LL) -------------------
__global__ __launch_bounds__(256, 4) void k_fwd(const __half* __restrict__ Ah,
                                                const float* __restrict__ wll,
                                                __half* __restrict__ LLh,
                                                __half* __restrict__ HSr,
                                                __half* __restrict__ HSi) {
    __shared__ float sx[32][52];
    __shared__ float slo[50][34];
    __shared__ float shi[50][34];
    int bc = blockIdx.x;
    int c = bc & 63;
    int tid = threadIdx.x;
    int hA = tid >> 3, w0r = (tid & 7) * 4;
    {
        const __half2* ap2 = (const __half2*)(Ah + (size_t)bc * 1024);
        __half2 v01 = ap2[tid * 2], v23 = ap2[tid * 2 + 1];
        sx[hA][w0r + 9] = __low2float(v01);
        sx[hA][w0r + 10] = __high2float(v01);
        sx[hA][w0r + 11] = __low2float(v23);
        sx[hA][w0r + 12] = __high2float(v23);
    }
    __syncthreads();
    for (int i = tid; i < 576; i += 256) {
        int h = i / 18, j = i - (i / 18) * 18;
        int wp = (j < 9) ? (j - 9) : (23 + j);
        sx[h][wp + 9] = sx[h][refl32(wp) + 9];
    }
    __syncthreads();
    {
        float ws[22];
#pragma unroll
        for (int t = 0; t < 22; ++t) ws[t] = sx[hA][w0r + t];
        float lo[4] = {0.f, 0.f, 0.f, 0.f}, hi[4] = {0.f, 0.f, 0.f, 0.f};
#pragma unroll
        for (int k = 0; k < 19; ++k)
#pragma unroll
            for (int j = 0; j < 4; ++j) hi[j] += H1c[k] * ws[j + k];
#pragma unroll
        for (int k = 0; k < 13; ++k)
#pragma unroll
            for (int j = 0; j < 4; ++j) lo[j] += H0c[k] * ws[j + k + 3];
#pragma unroll
        for (int j = 0; j < 4; ++j) {
            slo[hA + 9][w0r + j] = lo[j];
            shi[hA + 9][w0r + j] = hi[j];
        }
    }
    __syncthreads();
    for (int i = tid; i < 576; i += 256) {
        int j = i >> 5, w = i & 31;
        int hp = (j < 9) ? (j - 9) : (23 + j);
        int hs = refl32(hp);
        slo[hp + 9][w] = slo[hs + 9][w];
        shi[hp + 9][w] = shi[hs + 9][w];
    }
    __syncthreads();
    {
        int wL = tid & 31, h0 = (tid >> 5) * 4;
        float cs[16];
#pragma unroll
        for (int t = 0; t < 16; ++t) cs[t] = slo[h0 + 3 + t][wL];
#pragma unroll
        for (int j = 0; j < 4; ++j) {
            float acc = 0.f;
#pragma unroll
            for (int k = 0; k < 13; ++k) acc += H0c[k] * cs[j + k];
            int p = (h0 + j) * 32 + wL;
            LLh[(size_t)bc * 1024 + p] = __float2half(acc * wll[c * 1024 + p]);
        }
    }
    {
        int i = tid >> 4, j = tid & 15;
        size_t base = (size_t)bc * 1536 + tid;
        float a, bb, cc2, dd;
        {
            float2 sl[20];
#pragma unroll
            for (int t = 0; t < 20; ++t) sl[t] = *(const float2*)&slo[2 * i + t][2 * j];
            a = bb = cc2 = dd = 0.f;
#pragma unroll
            for (int k = 0; k < 19; ++k) {
                a += H1c[k] * sl[k].x;
                bb += H1c[k] * sl[k].y;
                cc2 += H1c[k] * sl[k + 1].x;
                dd += H1c[k] * sl[k + 1].y;
            }
            HSr[base + 0 * 256] = __float2half((a - dd) * ISQ2);
            HSi[base + 0 * 256] = __float2half((bb + cc2) * ISQ2);
            HSr[base + 5 * 256] = __float2half((a + dd) * ISQ2);
            HSi[base + 5 * 256] = __float2half((bb - cc2) * ISQ2);
        }
        {
            float2 sh[20];
#pragma unroll
            for (int t = 0; t < 20; ++t) sh[t] = *(const float2*)&shi[2 * i + t][2 * j];
            a = bb = cc2 = dd = 0.f;
#pragma unroll
            for (int k = 0; k < 19; ++k) {
                a += H1c[k] * sh[k].x;
                bb += H1c[k] * sh[k].y;
                cc2 += H1c[k] * sh[k + 1].x;
                dd += H1c[k] * sh[k + 1].y;
            }
            HSr[base + 1 * 256] = __float2half((a - dd) * ISQ2);
            HSi[base + 1 * 256] = __float2half((bb + cc2) * ISQ2);
            HSr[base + 4 * 256] = __float2half((a + dd) * ISQ2);
            HSi[base + 4 * 256] = __float2half((bb - cc2) * ISQ2);
            a = bb = cc2 = dd = 0.f;
#pragma unroll
            for (int k = 0; k < 13; ++k) {
                a += H0c[k] * sh[k + 3].x;
                bb += H0c[k] * sh[k + 3].y;
                cc2 += H0c[k] * sh[k + 4].x;
                dd += H0c[k] * sh[k + 4].y;
            }
            HSr[base + 2 * 256] = __float2half((a - dd) * ISQ2);
            HSi[base + 2 * 256] = __float2half((bb + cc2) * ISQ2);
            HSr[base + 3 * 256] = __float2half((a + dd) * ISQ2);
            HSi[base + 3 * 256] = __float2half((bb - cc2) * ISQ2);
        }
    }
}

// ---------------- K2b: prep complex-MLP fp16 B-frags (runs AFTER k_fwd) -------
__global__ __launch_bounds__(256) void k_prep_mlp(const float* __restrict__ mw1,
                                                  const float* __restrict__ mw2,
                                                  __half* __restrict__ W1cr,
                                                  __half* __restrict__ W1ci,
                                                  __half* __restrict__ W2cr,
                                                  __half* __restrict__ W2ci) {
    int gid = blockIdx.x * 256 + threadIdx.x;
    int stride = gridDim.x * 256;
    for (int i = gid; i < 2048; i += stride) {
        int q = i >> 9, rest = i & 511;
        int n = rest >> 5, k = rest & 31;
        if (k < 16) {
            W1cr[i] = __float2half(mw1[q * 256 + k * 16 + n]);
            W1ci[i] = __float2half(mw1[1024 + q * 256 + k * 16 + n]);
            W2cr[i] = __float2half(mw2[q * 256 + k * 16 + n]);
            W2ci[i] = __float2half(mw2[1024 + q * 256 + k * 16 + n]);
        } else {
            W1cr[i] = __float2half(-mw1[1024 + q * 256 + (k - 16) * 16 + n]);
            W1ci[i] = __float2half(mw1[q * 256 + (k - 16) * 16 + n]);
            W2cr[i] = __float2half(-mw2[1024 + q * 256 + (k - 16) * 16 + n]);
            W2ci[i] = __float2half(mw2[q * 256 + (k - 16) * 16 + n]);
        }
    }
}

// ---------------- K3: complex block-MLP via MFMA, fp16 HS in/out --------------
__global__ __launch_bounds__(256) void k_mlpm(__half* __restrict__ HSr,
                                              __half* __restrict__ HSi,
                                              const __half* __restrict__ W1cr,
                                              const __half* __restrict__ W1ci,
                                              const __half* __restrict__ W2cr,
                                              const __half* __restrict__ W2ci,
                                              const float* __restrict__ b1,
                                              const float* __restrict__ b2) {
    __shared__ __half xh[4][64][40];
    int tid = threadIdx.x;
    int wid = tid >> 6, lane = tid & 63;
    int lr = lane & 15, kg = lane >> 4;
    int b = blockIdx.x / 6;
    int o = blockIdx.x - b * 6;
    size_t base = (size_t)b * 98304 + (size_t)o * 256;

#pragma unroll 1
    for (int q = 0; q < 4; ++q) {
#pragma unroll
        for (int mt = 0; mt < 4; ++mt) {
            int token0 = wid * 64 + mt * 16;
            const unsigned short* src =
                (const unsigned short*)((kg < 2) ? HSr : HSi);
            int c0 = q * 16 + (kg & 1) * 8;
            unsigned int u[4];
#pragma unroll
            for (int e = 0; e < 4; ++e) {
                unsigned int lo = src[base + (size_t)(c0 + 2 * e) * 1536 + token0 + lr];
                unsigned int hi = src[base + (size_t)(c0 + 2 * e + 1) * 1536 + token0 + lr];
                u[e] = lo | (hi << 16);
            }
            uint4 av = make_uint4(u[0], u[1], u[2], u[3]);
            f16x8 a = *(f16x8*)&av;
            f16x8 bfr = *(const f16x8*)(W1cr + q * 512 + lr * 32 + kg * 8);
            f16x8 bfi = *(const f16x8*)(W1ci + q * 512 + lr * 32 + kg * 8);
            f32x4 accr = (f32x4){0.f, 0.f, 0.f, 0.f};
            f32x4 acci = (f32x4){0.f, 0.f, 0.f, 0.f};
            accr = __builtin_amdgcn_mfma_f32_16x16x32_f16(a, bfr, accr, 0, 0, 0);
            acci = __builtin_amdgcn_mfma_f32_16x16x32_f16(a, bfi, acci, 0, 0, 0);
            float b1r = b1[q * 16 + lr];
            float b1i = b1[64 + q * 16 + lr];
#pragma unroll
            for (int reg = 0; reg < 4; ++reg) {
                int tl = mt * 16 + kg * 4 + reg;
                xh[wid][tl][lr] = __float2half(fmaxf(accr[reg] + b1r, 0.f));
                xh[wid][tl][16 + lr] = __float2half(fmaxf(acci[reg] + b1i, 0.f));
            }
        }
        __syncthreads();
#pragma unroll
        for (int mt = 0; mt < 4; ++mt) {
            f16x8 a = *(const f16x8*)&xh[wid][mt * 16 + lr][kg * 8];
            f16x8 bfr = *(const f16x8*)(W2cr + q * 512 + lr * 32 + kg * 8);
            f16x8 bfi = *(const f16x8*)(W2ci + q * 512 + lr * 32 + kg * 8);
            f32x4 accr = (f32x4){0.f, 0.f, 0.f, 0.f};
            f32x4 acci = (f32x4){0.f, 0.f, 0.f, 0.f};
            accr = __builtin_amdgcn_mfma_f32_16x16x32_f16(a, bfr, accr, 0, 0, 0);
            acci = __builtin_amdgcn_mfma_f32_16x16x32_f16(a, bfi, acci, 0, 0, 0);
            float b2r = b2[q * 16 + lr];
            float b2i = b2[64 + q * 16 + lr];
            size_t cb = base + (size_t)(q * 16 + lr) * 1536 + wid * 64 + mt * 16 + kg * 4;
#pragma unroll
            for (int reg = 0; reg < 4; ++reg) {
                HSr[cb + reg] = __float2half(accr[reg] + b2r);
                HSi[cb + reg] = __float2half(acci[reg] + b2i);
            }
        }
        __syncthreads();
    }
}

// ------ K4: inverse DTCWT, fp16 io, synthesis planes aliased over analysis ----
__global__ __launch_bounds__(256, 4) void k_inv(const __half* __restrict__ LLh,
                                                const __half* __restrict__ HSr,
                                                const __half* __restrict__ HSi,
                                                __half* __restrict__ Yh) {
    __shared__ float sll[50][34], slh[50][34], shl[50][34], shh[50][34];
    // slo aliases sll (1664 <= 1700 floats); shi aliases shl.
    float (*slo)[52] = (float(*)[52])&sll[0][0];
    float (*shi)[52] = (float(*)[52])&shl[0][0];
    int bc = blockIdx.x;
    int tid = threadIdx.x;
    int hA = tid >> 3, w0r = (tid & 7) * 4;
    {
        const __half2* lp2 = (const __half2*)(LLh + (size_t)bc * 1024);
        __half2 v01 = lp2[tid * 2], v23 = lp2[tid * 2 + 1];
        sll[hA + 9][w0r] = __low2float(v01);
        sll[hA + 9][w0r + 1] = __high2float(v01);
        sll[hA + 9][w0r + 2] = __low2float(v23);
        sll[hA + 9][w0r + 3] = __high2float(v23);
    }
    {
        int i = tid >> 4, j = tid & 15;
        int h0 = 2 * i + 9, w0 = 2 * j;
        size_t base = (size_t)bc * 1536 + tid;
        float o0r = __half2float(HSr[base + 0 * 256]), o0i = __half2float(HSi[base + 0 * 256]);
        float o1r = __half2float(HSr[base + 1 * 256]), o1i = __half2float(HSi[base + 1 * 256]);
        float o2r = __half2float(HSr[base + 2 * 256]), o2i = __half2float(HSi[base + 2 * 256]);
        float o3r = __half2float(HSr[base + 3 * 256]), o3i = __half2float(HSi[base + 3 * 256]);
        float o4r = __half2float(HSr[base + 4 * 256]), o4i = __half2float(HSi[base + 4 * 256]);
        float o5r = __half2float(HSr[base + 5 * 256]), o5i = __half2float(HSi[base + 5 * 256]);
        *(float2*)&slh[h0][w0] = make_float2((o0r + o5r) * ISQ2, (o0i + o5i) * ISQ2);
        *(float2*)&slh[h0 + 1][w0] = make_float2((o0i - o5i) * ISQ2, (o5r - o0r) * ISQ2);
        *(float2*)&shl[h0][w0] = make_float2((o2r + o3r) * ISQ2, (o2i + o3i) * ISQ2);
        *(float2*)&shl[h0 + 1][w0] = make_float2((o2i - o3i) * ISQ2, (o3r - o2r) * ISQ2);
        *(float2*)&shh[h0][w0] = make_float2((o1r + o4r) * ISQ2, (o1i + o4i) * ISQ2);
        *(float2*)&shh[h0 + 1][w0] = make_float2((o1i - o4i) * ISQ2, (o4r - o1r) * ISQ2);
    }
    __syncthreads();
    for (int i = tid; i < 576; i += 256) {
        int j = i >> 5, w = i & 31;
        int hp = (j < 9) ? (j - 9) : (23 + j);
        int hs = refl32(hp);
        sll[hp + 9][w] = sll[hs + 9][w];
        slh[hp + 9][w] = slh[hs + 9][w];
        shl[hp + 9][w] = shl[hs + 9][w];
        shh[hp + 9][w] = shh[hs + 9][w];
    }
    __syncthreads();
    float lo[4], hi[4];
    int wL = tid & 31, h0c = (tid >> 5) * 4;
    {
        float w19[22], w13[16];
#pragma unroll
        for (int j = 0; j < 4; ++j) { lo[j] = 0.f; hi[j] = 0.f; }
#pragma unroll
        for (int t = 0; t < 22; ++t) w19[t] = sll[h0c + t][wL];
#pragma unroll
        for (int k = 0; k < 19; ++k) {
            float g0 = (k & 1) ? H1c[k] : -H1c[k];
#pragma unroll
            for (int j = 0; j < 4; ++j) lo[j] += g0 * w19[j + k];
        }
#pragma unroll
        for (int t = 0; t < 16; ++t) w13[t] = slh[h0c + 3 + t][wL];
#pragma unroll
        for (int k = 0; k < 13; ++k) {
            float g1 = (k & 1) ? H0c[k] : -H0c[k];
#pragma unroll
            for (int j = 0; j < 4; ++j) lo[j] += g1 * w13[j + k];
        }
#pragma unroll
        for (int t = 0; t < 22; ++t) w19[t] = shl[h0c + t][wL];
#pragma unroll
        for (int k = 0; k < 19; ++k) {
            float g0 = (k & 1) ? H1c[k] : -H1c[k];
#pragma unroll
            for (int j = 0; j < 4; ++j) hi[j] += g0 * w19[j + k];
        }
#pragma unroll
        for (int t = 0; t < 16; ++t) w13[t] = shh[h0c + 3 + t][wL];
#pragma unroll
        for (int k = 0; k < 13; ++k) {
            float g1 = (k & 1) ? H0c[k] : -H0c[k];
#pragma unroll
            for (int j = 0; j < 4; ++j) hi[j] += g1 * w13[j + k];
        }
    }
    // all reads of the analysis planes are done; now overwrite aliased storage
    __syncthreads();
#pragma unroll
    for (int j = 0; j < 4; ++j) {
        slo[h0c + j][wL + 9] = lo[j];
        shi[h0c + j][wL + 9] = hi[j];
    }
    __syncthreads();
    for (int i = tid; i < 576; i += 256) {
        int h = i / 18, j = i - (i / 18) * 18;
        int wp = (j < 9) ? (j - 9) : (23 + j);
        int ws2 = refl32(wp);
        slo[h][wp + 9] = slo[h][ws2 + 9];
        shi[h][wp + 9] = shi[h][ws2 + 9];
    }
    __syncthreads();
    {
        float rw[22], rh[16];
#pragma unroll
        for (int t = 0; t < 22; ++t) rw[t] = slo[hA][w0r + t];
#pragma unroll
        for (int t = 0; t < 16; ++t) rh[t] = shi[hA][w0r + 3 + t];
        float y[4] = {0.f, 0.f, 0.f, 0.f};
#pragma unroll
        for (int k = 0; k < 19; ++k) {
            float g0 = (k & 1) ? H1c[k] : -H1c[k];
#pragma unroll
            for (int j = 0; j < 4; ++j) y[j] += g0 * rw[j + k];
        }
#pragma unroll
        for (int k = 0; k < 13; ++k) {
            float g1 = (k & 1) ? H0c[k] : -H0c[k];
#pragma unroll
            for (int j = 0; j < 4; ++j) y[j] += g1 * rh[j + k];
        }
        __half2 y01 = __floats2half2_rn(y[0], y[1]);
        __half2 y23 = __floats2half2_rn(y[2], y[3]);
        uint2 pk;
        pk.x = *(unsigned int*)&y01;
        pk.y = *(unsigned int*)&y23;
        *(uint2*)(Yh + (size_t)bc * 1024 + hA * 32 + w0r) = pk;
    }
}

// ---------------- K4b: X1 = x + Y^T -> X1h fp16 (B,N,C) ----------------------
__global__ __launch_bounds__(256) void k_addt(const __half* __restrict__ Yh,
                                              const float* __restrict__ x,
                                              __half* __restrict__ X1h) {
    __shared__ float sy[64][65];
    int b = blockIdx.x >> 4;
    int n0 = (blockIdx.x & 15) << 6;
    int tid = threadIdx.x;
#pragma unroll
    for (int rep = 0; rep < 16; ++rep) {
        int idx = rep * 256 + tid;
        int c = idx >> 6, i = idx & 63;
        sy[c][i] = __half2float(Yh[((size_t)(b * 64 + c)) * 1024 + n0 + i]);
    }
    __syncthreads();
#pragma unroll
    for (int rep = 0; rep < 16; ++rep) {
        int idx = rep * 256 + tid;
        int i = idx >> 6, c = idx & 63;
        size_t gi = ((size_t)b * 1024 + n0 + i) * 64 + c;
        X1h[gi] = __float2half(x[gi] + sy[c][i]);
    }
}

// ---------------- K4c: zero the halo of padded H1 (b,k0,34,34,32) fp16 --------
__global__ __launch_bounds__(256) void k_halo(__half2* __restrict__ H1h2) {
    int img = blockIdx.x;  // 2048
    __half2* base = H1h2 + (size_t)img * 1156 * 16;
    __half2 z = __floats2half2_rn(0.f, 0.f);
    for (int idx = threadIdx.x; idx < 2112; idx += 256) {
        int pos = idx >> 4, c = idx & 15;
        int p2;
        if (pos < 34) p2 = pos;
        else if (pos < 68) p2 = 33 * 34 + (pos - 34);
        else if (pos < 100) p2 = (pos - 68 + 1) * 34;
        else p2 = (pos - 100 + 1) * 34 + 33;
        base[p2 * 16 + c] = z;
    }
}

// ---------------- K4d: prep LeFF fp16 weight tables (runs AFTER k_inv) --------
__global__ __launch_bounds__(256) void k_prep_leff(const float* __restrict__ DW,
                                                   const float* __restrict__ DB,
                                                   const float* __restrict__ W2,
                                                   const float* __restrict__ W1,
                                                   __half2* __restrict__ DWh,
                                                   __half2* __restrict__ DBh,
                                                   __half* __restrict__ W2T,
                                                   __half* __restrict__ W1T) {
    int gid = blockIdx.x * 256 + threadIdx.x;
    int stride = gridDim.x * 256;
    for (int i = gid; i < 1152; i += stride) {
        int tap = i >> 7, pr = i & 127;
        DWh[i] = __floats2half2_rn(DW[(2 * pr) * 9 + tap], DW[(2 * pr + 1) * 9 + tap]);
    }
    for (int i = gid; i < 128; i += stride)
        DBh[i] = __floats2half2_rn(DB[2 * i], DB[2 * i + 1]);
    for (int i = gid; i < 16384; i += stride) {
        int n = i >> 8, k = i & 255;
        W2T[i] = __float2half(W2[k * 64 + n]);
    }
    for (int i = gid; i < 16384; i += stride)
        W1T[i] = __float2half(W1[(i & 63) * 256 + (i >> 6)]);
}

// ---------------- K5: LN2 + lin1(MFMA fp16) + GELU -> H1 fp16 padded ----------
__global__ __launch_bounds__(256) void k_leff1m(const __half* __restrict__ X1h,
                                                const float* __restrict__ g2,
                                                const float* __restrict__ be2,
                                                const __half* __restrict__ W1T,
                                                const float* __restrict__ B1,
                                                __half* __restrict__ H1h) {
    __shared__ __half xnh[64][72];
    int tid = threadIdx.x;
    int wid = tid >> 6, lane = tid & 63;
    int lr = lane & 15, kg = lane >> 4;
    int bimg = blockIdx.x >> 4;
    int hw0 = (blockIdx.x & 15) << 6;
    size_t tok0 = (size_t)blockIdx.x * 64;
    int ltok = wid * 16 + lr;
    {
        const uint4* xp = (const uint4*)(X1h + (tok0 + ltok) * 64 + kg * 16);
        uint4 q0 = xp[0], q1 = xp[1];
        unsigned int uu[8] = {q0.x, q0.y, q0.z, q0.w, q1.x, q1.y, q1.z, q1.w};
        float vv[16];
#pragma unroll
        for (int i = 0; i < 8; ++i) {
            __half2 h = u2h2(uu[i]);
            vv[2 * i] = __low2float(h);
            vv[2 * i + 1] = __high2float(h);
        }
        float s = 0.f, ss = 0.f;
#pragma unroll
        for (int i = 0; i < 16; ++i) {
            s += vv[i];
            ss += vv[i] * vv[i];
        }
        s += __shfl_xor(s, 16, 64);
        ss += __shfl_xor(ss, 16, 64);
        s += __shfl_xor(s, 32, 64);
        ss += __shfl_xor(ss, 32, 64);
        float m = s * (1.f / 64.f);
        float var = ss * (1.f / 64.f) - m * m;
        float rstd = rsqrtf(var + 1e-5f);
        unsigned int u[8];
#pragma unroll
        for (int i = 0; i < 8; ++i) {
            int d = kg * 16 + 2 * i;
            float a0 = (vv[2 * i] - m) * rstd * g2[d] + be2[d];
            float a1 = (vv[2 * i + 1] - m) * rstd * g2[d + 1] + be2[d + 1];
            __half2 hh = __floats2half2_rn(a0, a1);
            u[i] = *(unsigned int*)&hh;
        }
        *(uint4*)&xnh[ltok][kg * 16] = make_uint4(u[0], u[1], u[2], u[3]);
        *(uint4*)&xnh[ltok][kg * 16 + 8] = make_uint4(u[4], u[5], u[6], u[7]);
    }
    __syncthreads();
    f32x4 acc[16];
#pragma unroll
    for (int n = 0; n < 16; ++n) acc[n] = (f32x4){0.f, 0.f, 0.f, 0.f};
#pragma unroll
    for (int k0 = 0; k0 < 2; ++k0) {
        f16x8 a = *(const f16x8*)&xnh[wid * 16 + lr][k0 * 32 + kg * 8];
#pragma unroll
        for (int n = 0; n < 16; ++n) {
            f16x8 bf = *(const f16x8*)(W1T + (size_t)(n * 16 + lr) * 64 + k0 * 32 + kg * 8);
            acc[n] = __builtin_amdgcn_mfma_f32_16x16x32_f16(a, bf, acc[n], 0, 0, 0);
        }
    }
#pragma unroll
    for (int n = 0; n < 16; ++n) {
        int hid = n * 16 + lr;
        float bb = B1[hid];
        size_t cb = ((size_t)bimg * 8 + (hid >> 5)) * 1156;
        int cl = hid & 31;
#pragma unroll
        for (int reg = 0; reg < 4; ++reg) {
            int token = wid * 16 + kg * 4 + reg;
            int hw = hw0 + token;
            int h = hw >> 5, w = hw & 31;
            H1h[(cb + (size_t)(h + 1) * 34 + (w + 1)) * 32 + cl] =
                __float2half(gelu_fast(acc[n][reg] + bb));
        }
    }
}

// ---------------- K6: fused dwconv+GELU+lin2(MFMA), 2 rows/wave ---------------
struct Tap12 { uint4 v[12]; };

__device__ __forceinline__ void load12(const __half* H1h, size_t pb, int kg, Tap12& T) {
    const __half2* p = (const __half2*)(H1h + pb * 32) + kg * 4;
#pragma unroll
    for (int r = 0; r < 4; ++r)
#pragma unroll
        for (int dc = 0; dc < 3; ++dc)
            T.v[r * 3 + dc] = *(const uint4*)(p + ((r - 1) * 34 + (dc - 1)) * 16);
}

__device__ __forceinline__ void convg2(const Tap12& T,
                                       const __half2* __restrict__ DBh,
                                       const __half2* __restrict__ DWh,
                                       int k0, int kg, f16x8& a0out, f16x8& a1out) {
    const __half2* dbp = DBh + k0 * 16 + kg * 4;
    __half2 c00 = dbp[0], c01 = dbp[1], c02 = dbp[2], c03 = dbp[3];
    __half2 c10 = c00, c11 = c01, c12 = c02, c13 = c03;
#pragma unroll
    for (int dr = 0; dr < 3; ++dr) {
#pragma unroll
        for (int dc = 0; dc < 3; ++dc) {
            const __half2* wp = DWh + (dr * 3 + dc) * 128 + k0 * 16 + kg * 4;
            __half2 w0 = wp[0], w1 = wp[1], w2 = wp[2], w3 = wp[3];
            const uint4& t0 = T.v[dr * 3 + dc];
            const uint4& t1 = T.v[(dr + 1) * 3 + dc];
            c00 = __hfma2(u2h2(t0.x), w0, c00);
            c01 = __hfma2(u2h2(t0.y), w1, c01);
            c02 = __hfma2(u2h2(t0.z), w2, c02);
            c03 = __hfma2(u2h2(t0.w), w3, c03);
            c10 = __hfma2(u2h2(t1.x), w0, c10);
            c11 = __hfma2(u2h2(t1.y), w1, c11);
            c12 = __hfma2(u2h2(t1.z), w2, c12);
            c13 = __hfma2(u2h2(t1.w), w3, c13);
        }
    }
    __half2 o0 = __floats2half2_rn(gelu_fast(__low2float(c00)), gelu_fast(__high2float(c00)));
    __half2 o1 = __floats2half2_rn(gelu_fast(__low2float(c01)), gelu_fast(__high2float(c01)));
    __half2 o2 = __floats2half2_rn(gelu_fast(__low2float(c02)), gelu_fast(__high2float(c02)));
    __half2 o3 = __floats2half2_rn(gelu_fast(__low2float(c03)), gelu_fast(__high2float(c03)));
    uint4 av0 = make_uint4(*(unsigned int*)&o0, *(unsigned int*)&o1,
                           *(unsigned int*)&o2, *(unsigned int*)&o3);
    a0out = *(f16x8*)&av0;
    o0 = __floats2half2_rn(gelu_fast(__low2float(c10)), gelu_fast(__high2float(c10)));
    o1 = __floats2half2_rn(gelu_fast(__low2float(c11)), gelu_fast(__high2float(c11)));
    o2 = __floats2half2_rn(gelu_fast(__low2float(c12)), gelu_fast(__high2float(c12)));
    o3 = __floats2half2_rn(gelu_fast(__low2float(c13)), gelu_fast(__high2float(c13)));
    uint4 av1 = make_uint4(*(unsigned int*)&o0, *(unsigned int*)&o1,
                           *(unsigned int*)&o2, *(unsigned int*)&o3);
    a1out = *(f16x8*)&av1;
}

__global__ __launch_bounds__(256, 3) void k_leff2m(const __half* __restrict__ H1h,
                                                   const __half2* __restrict__ DWh,
                                                   const __half2* __restrict__ DBh,
                                                   const __half* __restrict__ W2T,
                                                   const float* __restrict__ B2,
                                                   const __half* __restrict__ X1h,
                                                   float* __restrict__ out) {
    int tid = threadIdx.x;
    int wid = tid >> 6, lane = tid & 63;
    int mt = blockIdx.x * 4 + wid;   // 0..8191
    int b = mt >> 5;
    int rem = mt & 31;
    int h0 = (rem >> 1) * 2;
    int w0 = (rem & 1) << 4;
    int lr = lane & 15, kg = lane >> 4;
    int wA = w0 + lr;

    f32x4 acc0[4], acc1[4];
#pragma unroll
    for (int n = 0; n < 4; ++n) {
        acc0[n] = (f32x4){0.f, 0.f, 0.f, 0.f};
        acc1[n] = (f32x4){0.f, 0.f, 0.f, 0.f};
    }

    size_t rowoff = (size_t)h0 * 34 + wA;
    Tap12 TA, TB;
    load12(H1h, ((size_t)b * 8 + 0) * 1156 + rowoff + 35, kg, TA);
#pragma unroll
    for (int k0 = 0; k0 < 8; ++k0) {
        if (k0 < 7)
            load12(H1h, ((size_t)b * 8 + (k0 + 1)) * 1156 + rowoff + 35, kg,
                   (k0 & 1) ? TA : TB);
        f16x8 a0, a1;
        convg2((k0 & 1) ? TB : TA, DBh, DWh, k0, kg, a0, a1);
#pragma unroll
        for (int n = 0; n < 4; ++n) {
            f16x8 bf = *(const f16x8*)(W2T + ((size_t)(n * 16 + lr) * 256 + k0 * 32 + kg * 8));
            acc0[n] = __builtin_amdgcn_mfma_f32_16x16x32_f16(a0, bf, acc0[n], 0, 0, 0);
            acc1[n] = __builtin_amdgcn_mfma_f32_16x16x32_f16(a1, bf, acc1[n], 0, 0, 0);
        }
    }
    size_t ob0 = (size_t)b * 1024 + (size_t)h0 * 32;
#pragma unroll
    for (int n = 0; n < 4; ++n) {
        int c = n * 16 + lr;
        float b2v = B2[c];
#pragma unroll
        for (int reg = 0; reg < 4; ++reg) {
            int rowTok = w0 + kg * 4 + reg;
            size_t g0i = (ob0 + rowTok) * 64 + c;
            out[g0i] = __half2float(X1h[g0i]) + acc0[n][reg] + b2v;
            size_t g1i = (ob0 + 32 + rowTok) * 64 + c;
            out[g1i] = __half2float(X1h[g1i]) + acc1[n][reg] + b2v;
        }
    }
}

extern "C" void kernel_launch(void* const* d_in, const int* in_sizes, int n_in,
                              void* d_out, int out_size, void* d_ws, size_t ws_size,
                              hipStream_t stream) {
    const float* x = (const float*)d_in[0];
    const float* ln1_g = (const float*)d_in[1];
    const float* ln1_b = (const float*)d_in[2];
    const float* w_ll = (const float*)d_in[3];
    const float* w1 = (const float*)d_in[4];
    const float* w2 = (const float*)d_in[5];
    const float* b1 = (const float*)d_in[6];
    const float* b2 = (const float*)d_in[7];
    const float* ln2_g = (const float*)d_in[8];
    const float* ln2_b = (const float*)d_in[9];
    const float* lin1_w = (const float*)d_in[10];
    const float* lin1_b = (const float*)d_in[11];
    const float* dw_w = (const float*)d_in[12];
    const float* dw_b = (const float*)d_in[13];
    const float* lin2_w = (const float*)d_in[14];
    const float* lin2_b = (const float*)d_in[15];
    float* out = (float*)d_out;
    char* ws = (char*)d_ws;

    // Lifetimes:
    //  Ah   [0, 33.5MB)       : LN1 out; dead after k_fwd. Reused: mlp tables, Yh, H1h.
    //  HSr  [64MiB, 112MiB)   : live k_fwd..k_inv.
    //  HSi  [160MiB, 208MiB)  : live k_fwd..k_inv. Reused after inv: leff tables.
    //  LLh  [208MiB, +33.5MB) : k_fwd writes, k_inv reads; tail untouched by HS.
    //  Yh   [0, 33.5MB)       : k_inv writes, k_addt reads; dead before k_halo.
    //  X1h  [208MiB, +33.5MB) : k_addt writes (after inv; LLh dead), read by
    //                           k_leff1m and k_leff2m. No overlap with H1h/wtab.
    //  H1h  [0, 144.5MiB)     : k_halo/k_leff1m write, k_leff2m reads.
    __half* Ah = (__half*)ws;
    __half* HSr = (__half*)(ws + 67108864);
    __half* HSi = (__half*)(ws + 167772160);
    __half* LLh = (__half*)(ws + 218103808);
    __half* Yh = (__half*)ws;
    __half* X1h = (__half*)(ws + 218103808);
    __half* H1h = (__half*)ws;
    __half* W1cr = (__half*)(ws);
    __half* W1ci = (__half*)(ws + 4096);
    __half* W2cr = (__half*)(ws + 8192);
    __half* W2ci = (__half*)(ws + 12288);
    char* wtab = ws + 167772160;
    __half2* DWh = (__half2*)(wtab);
    __half2* DBh = (__half2*)(wtab + 8192);
    __half* W2T = (__half*)(wtab + 12288);
    __half* W1T = (__half*)(wtab + 49152);

    k_ln1_t<<<dim3(4096), dim3(256), 0, stream>>>(x, ln1_g, ln1_b, Ah);
    k_fwd<<<dim3(16384), dim3(256), 0, stream>>>(Ah, w_ll, LLh, HSr, HSi);
    k_prep_mlp<<<dim3(8), dim3(256), 0, stream>>>(w1, w2, W1cr, W1ci, W2cr, W2ci);
    k_mlpm<<<dim3(1536), dim3(256), 0, stream>>>(HSr, HSi, W1cr, W1ci, W2cr, W2ci, b1, b2);
    k_inv<<<dim3(16384), dim3(256), 0, stream>>>(LLh, HSr, HSi, Yh);
    k_addt<<<dim3(4096), dim3(256), 0, stream>>>(Yh, x, X1h);
    k_halo<<<dim3(2048), dim3(256), 0, stream>>>((__half2*)H1h);
    k_prep_leff<<<dim3(72), dim3(256), 0, stream>>>(dw_w, dw_b, lin2_w, lin1_w,
                                                    DWh, DBh, W2T, W1T);
    k_leff1m<<<dim3(4096), dim3(256), 0, stream>>>(X1h, ln2_g, ln2_b, W1T, lin1_b, H1h);
    k_leff2m<<<dim3(2048), dim3(256), 0, stream>>>(H1h, DWh, DBh, W2T, b2, X1h, out);
}